// Round 3
// baseline (986.986 us; speedup 1.0000x reference)
//
#include <hip/hip_runtime.h>
#include <hip/hip_bf16.h>

#define D 128
#define NL 3
#define NODE_SH 8            // 256 nodes per bucket
#define NB_MAX 512
#define BIN_CHUNK 4096

typedef __attribute__((ext_vector_type(8))) short short8;
typedef __attribute__((ext_vector_type(4))) float f32x4;

static inline size_t align256(size_t x){ return (x + 255) & ~(size_t)255; }

static __device__ inline unsigned short f2bf_hi(float f){
    __hip_bfloat16 h = __float2bfloat16(f);          // RNE
    return *reinterpret_cast<unsigned short*>(&h);
}
static __device__ inline float bf2f(unsigned short u){
    return __uint_as_float(((unsigned)u) << 16);
}

// ---------------- embedding gather: x[n] = z_table[z[n]] ----------------
__global__ __launch_bounds__(256) void k_embed(const int* __restrict__ z, const float* __restrict__ zt,
                                               float* __restrict__ x, int N){
    int i = blockIdx.x * blockDim.x + threadIdx.x;   // over N*32 float4s
    int n = i >> 5, q = i & 31;
    if (n >= N) return;
    float4 v = *(const float4*)&zt[(size_t)z[n] * D + q * 4];
    *(float4*)&x[(size_t)n * D + q * 4] = v;
}

// ---------------- degree count ----------------
__global__ __launch_bounds__(256) void k_deg(const int* __restrict__ dst, int* __restrict__ deg, int E){
    int e = blockIdx.x * blockDim.x + threadIdx.x;
    if (e < E) atomicAdd(&deg[dst[e]], 1);
}

__global__ __launch_bounds__(256) void k_invdeg(const int* __restrict__ deg, float* __restrict__ invdeg, int N){
    int n = blockIdx.x * blockDim.x + threadIdx.x;
    if (n < N) invdeg[n] = 1.0f / (float)max(deg[n], 1);
}

// ---------------- exclusive scan of deg -> offs (3-kernel) ----------------
#define SCAN_B 512
__global__ __launch_bounds__(SCAN_B) void k_scan1(const int* __restrict__ deg, int* __restrict__ bsum, int N){
    __shared__ int s[SCAN_B];
    int i = blockIdx.x * SCAN_B + threadIdx.x;
    s[threadIdx.x] = (i < N) ? deg[i] : 0;
    __syncthreads();
    for (int st = SCAN_B / 2; st > 0; st >>= 1){
        if (threadIdx.x < st) s[threadIdx.x] += s[threadIdx.x + st];
        __syncthreads();
    }
    if (threadIdx.x == 0) bsum[blockIdx.x] = s[0];
}

__global__ __launch_bounds__(SCAN_B) void k_scan2(int* __restrict__ bsum, int nb){
    __shared__ int s[SCAN_B];
    int t = threadIdx.x;
    int v = (t < nb) ? bsum[t] : 0;
    s[t] = v; __syncthreads();
    for (int st = 1; st < SCAN_B; st <<= 1){
        int u = (t >= st) ? s[t - st] : 0;
        __syncthreads();
        s[t] += u;
        __syncthreads();
    }
    if (t < nb) bsum[t] = s[t] - v;   // exclusive
}

__global__ __launch_bounds__(SCAN_B) void k_scan3(const int* __restrict__ deg, const int* __restrict__ bsum,
                                                  int* __restrict__ offs, int N, int E){
    __shared__ int s[SCAN_B];
    int i = blockIdx.x * SCAN_B + threadIdx.x;
    int v = (i < N) ? deg[i] : 0;
    s[threadIdx.x] = v; __syncthreads();
    for (int st = 1; st < SCAN_B; st <<= 1){
        int u = (threadIdx.x >= st) ? s[threadIdx.x - st] : 0;
        __syncthreads();
        s[threadIdx.x] += u;
        __syncthreads();
    }
    if (i < N) offs[i] = s[threadIdx.x] - v + bsum[blockIdx.x];
    if (blockIdx.x == 0 && threadIdx.x == 0) offs[N] = E;
}

// ---------------- bucket cursor init: gcur[b] = offs[b*256] ----------------
__global__ __launch_bounds__(256) void k_bcur(const int* __restrict__ offs, int* __restrict__ gcur,
                                              int NB, int N){
    int b = blockIdx.x * blockDim.x + threadIdx.x;
    if (b < NB) gcur[b] = offs[min(b << NODE_SH, N)];
}

// ---------------- pass A: bin edges by dst-bucket with LDS reorder ----------------
// writes packed (src | dst_local<<17) into bucket-major ebuf2, bucket-ordered runs
__global__ __launch_bounds__(256) void k_binA(const int* __restrict__ src, const int* __restrict__ dst,
                                              int* __restrict__ gcur, int* __restrict__ ebuf2,
                                              int E, int NB){
    __shared__ int s_hist[NB_MAX];
    __shared__ int s_lofs[NB_MAX];
    __shared__ int s_delta[NB_MAX];
    __shared__ int s_pack[BIN_CHUNK];
    __shared__ int s_gdst[BIN_CHUNK];
    __shared__ int s_scan[256];
    const int t = threadIdx.x;
    const int e0 = blockIdx.x * BIN_CHUNK;
    for (int b = t; b < NB_MAX; b += 256) s_hist[b] = 0;
    __syncthreads();
    int my_pack[16], my_b[16], my_rank[16];
    #pragma unroll
    for (int i = 0; i < 16; ++i){
        int e = e0 + i * 256 + t;
        if (e < E){
            int s = src[e], d = dst[e];
            int b = d >> NODE_SH;
            my_pack[i] = s | ((d & 255) << 17);
            my_b[i] = b;
            my_rank[i] = atomicAdd(&s_hist[b], 1);
        } else my_b[i] = -1;
    }
    __syncthreads();
    // exclusive scan of s_hist over NB_MAX (2 entries per thread)
    int h0 = s_hist[2 * t], h1 = s_hist[2 * t + 1];
    int sum2 = h0 + h1;
    s_scan[t] = sum2;
    __syncthreads();
    for (int st = 1; st < 256; st <<= 1){
        int v = (t >= st) ? s_scan[t - st] : 0;
        __syncthreads();
        s_scan[t] += v;
        __syncthreads();
    }
    int excl = s_scan[t] - sum2;
    s_lofs[2 * t] = excl;
    s_lofs[2 * t + 1] = excl + h0;
    __syncthreads();
    // reserve disjoint global ranges per bucket
    for (int b = t; b < NB; b += 256){
        int h = s_hist[b];
        int base = (h > 0) ? atomicAdd(&gcur[b], h) : 0;
        s_delta[b] = base - s_lofs[b];
    }
    __syncthreads();
    // reorder into LDS by bucket
    #pragma unroll
    for (int i = 0; i < 16; ++i){
        if (my_b[i] >= 0){
            int j = s_lofs[my_b[i]] + my_rank[i];
            s_pack[j] = my_pack[i];
            s_gdst[j] = j + s_delta[my_b[i]];
        }
    }
    __syncthreads();
    const int cnt = min(BIN_CHUNK, E - e0);
    for (int j = t; j < cnt; j += 256)
        ebuf2[s_gdst[j]] = s_pack[j];
}

// ---------------- pass B: per-bucket CSR fill (block owns its ebuf region) ----------------
__global__ __launch_bounds__(256) void k_binB(const int* __restrict__ ebuf2, const int* __restrict__ offs,
                                              int* __restrict__ ebuf, int N){
    __shared__ int lcur[256];
    const int b = blockIdx.x, t = threadIdx.x;
    const int n0 = b << NODE_SH;
    const int n1 = min(n0 + 256, N);
    if (n0 + t < n1) lcur[t] = offs[n0 + t];
    __syncthreads();
    const int rs = offs[n0], re = offs[n1];
    for (int i = rs + t; i < re; i += 256){
        int v = ebuf2[i];
        int p = atomicAdd(&lcur[v >> 17], 1);
        ebuf[p] = v & 0x1FFFF;
    }
}

// ---------------- segment starts ----------------
__global__ __launch_bounds__(256) void k_centers(const int* __restrict__ batch, int* __restrict__ centers, int N){
    int n = blockIdx.x * blockDim.x + threadIdx.x;
    if (n < N && (n == 0 || batch[n] != batch[n - 1])) centers[batch[n]] = n;
}

// ---------------- weight prep: split-bf16 B matrices [l][d][k], W1T ----------------
__global__ __launch_bounds__(256) void k_prepW(const float* __restrict__ Wl, const float* __restrict__ Wr,
                                               const float* __restrict__ W1, float* __restrict__ W1T,
                                               unsigned short* __restrict__ WBh, unsigned short* __restrict__ WBl){
    int i = blockIdx.x * blockDim.x + threadIdx.x;
    if (i < NL * D * 2 * D){
        int l = i / (D * 2 * D); int r = i % (D * 2 * D); int d = r / (2 * D); int k = r % (2 * D);
        float w = (k < D) ? Wl[(size_t)l * D * D + d * D + k]
                          : Wr[(size_t)l * D * D + d * D + (k - D)];
        unsigned short h = f2bf_hi(w);
        WBh[i] = h;
        WBl[i] = f2bf_hi(w - bf2f(h));
    }
    if (i < D * D){ int k = i / D, d = i % D; W1T[i] = W1[d * D + k]; }
}

// ---------------- mean aggregation (gather over CSR) ----------------
__global__ __launch_bounds__(256) void k_agg(const float* __restrict__ x, const int* __restrict__ ebuf,
                                             const int* __restrict__ offs, const float* __restrict__ invdeg,
                                             float* __restrict__ agg, int N){
    int node = blockIdx.x * 8 + (threadIdx.x >> 5);
    if (node >= N) return;
    int lane = threadIdx.x & 31;
    int s = offs[node], e = offs[node + 1];
    const float4* x4 = (const float4*)x;
    float4 acc = make_float4(0.f, 0.f, 0.f, 0.f);
    for (int i = s; i < e; ++i){
        int nb = ebuf[i];
        float4 v = x4[(size_t)nb * 32 + lane];
        acc.x += v.x; acc.y += v.y; acc.z += v.z; acc.w += v.w;
    }
    float sc = invdeg[node];
    acc.x *= sc; acc.y *= sc; acc.z *= sc; acc.w *= sc;
    ((float4*)agg)[(size_t)node * 32 + lane] = acc;
}

// ---------------- fused dense via split-bf16 MFMA ----------------
// Out[N,128] = [agg | x] (N,256) @ WB (256,128) + bias, optional relu.
// Block: 512 thr (8 waves), 128 rows/block, wave w owns rows w*16..w*16+15, all 128 cols.
// a = ah + al, b = bh + bl (bf16 RNE split); acc += ah*bh + al*bh + ah*bl.
template<bool RELU>
__global__ __launch_bounds__(512) void k_dense_mfma(const float* __restrict__ Ag, const float* __restrict__ X,
                                                    const unsigned short* __restrict__ WBh,
                                                    const unsigned short* __restrict__ WBl,
                                                    const float* __restrict__ bias,
                                                    float* __restrict__ Out, int N){
    const int wave = threadIdx.x >> 6;
    const int lane = threadIdx.x & 63;
    const int l15  = lane & 15;
    const int kg   = lane >> 4;          // 0..3
    const int row0 = blockIdx.x * 128 + wave * 16 + l15;
    const int rowc = min(row0, N - 1);   // clamp for loads

    f32x4 acc[8];
    #pragma unroll
    for (int fn = 0; fn < 8; ++fn) acc[fn] = (f32x4){0.f, 0.f, 0.f, 0.f};

    #pragma unroll
    for (int ks = 0; ks < 8; ++ks){
        const float* S = (ks < 4) ? Ag : X;
        const int ko = (ks & 3) * 32 + kg * 8;
        const float* ap = &S[(size_t)rowc * D + ko];
        float4 a0 = *(const float4*)ap;
        float4 a1 = *(const float4*)(ap + 4);
        float av[8] = {a0.x, a0.y, a0.z, a0.w, a1.x, a1.y, a1.z, a1.w};
        short8 ah, al;
        #pragma unroll
        for (int j = 0; j < 8; ++j){
            unsigned short h = f2bf_hi(av[j]);
            ah[j] = (short)h;
            al[j] = (short)f2bf_hi(av[j] - bf2f(h));
        }
        const int kb = ks * 32 + kg * 8;
        #pragma unroll
        for (int fn = 0; fn < 8; ++fn){
            const int col = fn * 16 + l15;
            const short8 bh = *(const short8*)&WBh[(size_t)col * 256 + kb];
            const short8 bl = *(const short8*)&WBl[(size_t)col * 256 + kb];
            acc[fn] = __builtin_amdgcn_mfma_f32_16x16x32_bf16(ah, bh, acc[fn], 0, 0, 0);
            acc[fn] = __builtin_amdgcn_mfma_f32_16x16x32_bf16(al, bh, acc[fn], 0, 0, 0);
            acc[fn] = __builtin_amdgcn_mfma_f32_16x16x32_bf16(ah, bl, acc[fn], 0, 0, 0);
        }
    }
    // epilogue: C/D layout col=lane&15, row=(lane>>4)*4+reg  [m89 verified]
    const int rbase = blockIdx.x * 128 + wave * 16 + (kg << 2);
    #pragma unroll
    for (int fn = 0; fn < 8; ++fn){
        const int col = fn * 16 + l15;
        const float bv = bias[col];
        #pragma unroll
        for (int r = 0; r < 4; ++r){
            const int orow = rbase + r;
            if (orow < N){
                float v = acc[fn][r] + bv;
                if (RELU) v = fmaxf(v, 0.f);
                Out[(size_t)orow * D + col] = v;
            }
        }
    }
}

// ---------------- head: out[g] = W2 @ relu(W1 @ (x[c]*x[c+1]) + b1) + b2 ----------------
__global__ __launch_bounds__(128) void k_head(const float* __restrict__ x, const int* __restrict__ centers,
                                              const float* __restrict__ W1T, const float* __restrict__ b1,
                                              const float* __restrict__ W2, const float* __restrict__ b2,
                                              float* __restrict__ out){
    __shared__ float hs[D];
    __shared__ float red[D];
    int g = blockIdx.x; int d = threadIdx.x;
    int c = centers[g];
    hs[d] = x[(size_t)c * D + d] * x[(size_t)(c + 1) * D + d];
    __syncthreads();
    float acc = b1[d];
    #pragma unroll 8
    for (int k = 0; k < D; ++k) acc = fmaf(hs[k], W1T[k * D + d], acc);
    acc = fmaxf(acc, 0.f);
    red[d] = acc * W2[d];
    __syncthreads();
    for (int st = 64; st > 0; st >>= 1){
        if (d < st) red[d] += red[d + st];
        __syncthreads();
    }
    if (d == 0) out[g] = red[0] + b2[0];
}

extern "C" void kernel_launch(void* const* d_in, const int* in_sizes, int n_in,
                              void* d_out, int out_size, void* d_ws, size_t ws_size,
                              hipStream_t stream){
    const int*   z     = (const int*)  d_in[0];
    const int*   eidx  = (const int*)  d_in[1];
    const int*   batch = (const int*)  d_in[2];
    const float* zt    = (const float*)d_in[3];
    const float* Wl    = (const float*)d_in[4];
    const float* bl    = (const float*)d_in[5];
    const float* Wr    = (const float*)d_in[6];
    const float* W1    = (const float*)d_in[7];
    const float* b1    = (const float*)d_in[8];
    const float* W2    = (const float*)d_in[9];
    const float* b2    = (const float*)d_in[10];
    float* out = (float*)d_out;

    const int N = in_sizes[0];
    const int E = in_sizes[1] / 2;
    const int G = out_size;
    const int NB = (N + 255) >> NODE_SH;
    const int* src  = eidx;
    const int* dstp = eidx + E;

    char* p = (char*)d_ws;
    auto alloc = [&](size_t bytes){ char* r = p; p += align256(bytes); return r; };
    float* xa      = (float*)alloc((size_t)N * D * 4);
    float* xb      = (float*)alloc((size_t)N * D * 4);
    float* agg     = (float*)alloc((size_t)N * D * 4);
    int*   deg     = (int*)  alloc((size_t)N * 4);
    float* invdeg  = (float*)alloc((size_t)N * 4);
    int*   offs    = (int*)  alloc((size_t)(N + 1) * 4);
    int*   ebuf    = (int*)  alloc((size_t)E * 4);
    int*   ebuf2   = (int*)  alloc((size_t)E * 4);
    int*   centers = (int*)  alloc((size_t)G * 4);
    int*   bsum    = (int*)  alloc((size_t)1024 * 4);
    int*   gcur    = (int*)  alloc((size_t)NB_MAX * 4);
    float* W1T     = (float*)alloc((size_t)D * D * 4);
    unsigned short* WBh = (unsigned short*)alloc((size_t)NL * D * 2 * D * 2);
    unsigned short* WBl = (unsigned short*)alloc((size_t)NL * D * 2 * D * 2);
    (void)ws_size; (void)n_in;

    hipMemsetAsync(deg, 0, (size_t)N * 4, stream);
    k_embed<<<(N * 32 + 255) / 256, 256, 0, stream>>>(z, zt, xa, N);
    k_deg<<<(E + 255) / 256, 256, 0, stream>>>(dstp, deg, E);
    k_invdeg<<<(N + 255) / 256, 256, 0, stream>>>(deg, invdeg, N);
    int nb1 = (N + SCAN_B - 1) / SCAN_B;
    k_scan1<<<nb1, SCAN_B, 0, stream>>>(deg, bsum, N);
    k_scan2<<<1, SCAN_B, 0, stream>>>(bsum, nb1);
    k_scan3<<<nb1, SCAN_B, 0, stream>>>(deg, bsum, offs, N, E);
    k_bcur<<<(NB + 255) / 256, 256, 0, stream>>>(offs, gcur, NB, N);
    k_binA<<<(E + BIN_CHUNK - 1) / BIN_CHUNK, 256, 0, stream>>>(src, dstp, gcur, ebuf2, E, NB);
    k_binB<<<NB, 256, 0, stream>>>(ebuf2, offs, ebuf, N);
    k_centers<<<(N + 255) / 256, 256, 0, stream>>>(batch, centers, N);
    k_prepW<<<(NL * D * 2 * D + 255) / 256, 256, 0, stream>>>(Wl, Wr, W1, W1T, WBh, WBl);

    float* xc = xa; float* xn = xb;
    for (int l = 0; l < NL; ++l){
        k_agg<<<(N + 7) / 8, 256, 0, stream>>>(xc, ebuf, offs, invdeg, agg, N);
        const unsigned short* wh = WBh + (size_t)l * D * 2 * D;
        const unsigned short* wl = WBl + (size_t)l * D * 2 * D;
        if (l < NL - 1)
            k_dense_mfma<true ><<<(N + 127) / 128, 512, 0, stream>>>(agg, xc, wh, wl, bl + l * D, xn, N);
        else
            k_dense_mfma<false><<<(N + 127) / 128, 512, 0, stream>>>(agg, xc, wh, wl, bl + l * D, xn, N);
        float* t = xc; xc = xn; xn = t;
    }
    k_head<<<G, 128, 0, stream>>>(xc, centers, W1T, b1, W2, b2, out);
}

// Round 4
// 766.558 us; speedup vs baseline: 1.2876x; 1.2876x over previous
//
#include <hip/hip_runtime.h>
#include <hip/hip_bf16.h>

#define D 128
#define NL 3
#define NODE_SH 8            // 256 nodes per bucket
#define NB_MAX 512
#define BIN_CHUNK 4096

typedef __attribute__((ext_vector_type(8))) short short8;
typedef __attribute__((ext_vector_type(4))) float f32x4;

static inline size_t align256(size_t x){ return (x + 255) & ~(size_t)255; }

static __device__ inline unsigned short f2bf_hi(float f){
    __hip_bfloat16 h = __float2bfloat16(f);          // RNE
    return *reinterpret_cast<unsigned short*>(&h);
}
static __device__ inline float bf2f(unsigned short u){
    return __uint_as_float(((unsigned)u) << 16);
}

// ---------------- embedding gather: x[n] = z_table[z[n]] ----------------
__global__ __launch_bounds__(256) void k_embed(const int* __restrict__ z, const float* __restrict__ zt,
                                               float* __restrict__ x, int N){
    int i = blockIdx.x * blockDim.x + threadIdx.x;   // over N*32 float4s
    int n = i >> 5, q = i & 31;
    if (n >= N) return;
    float4 v = *(const float4*)&zt[(size_t)z[n] * D + q * 4];
    *(float4*)&x[(size_t)n * D + q * 4] = v;
}

// ---------------- degree count ----------------
__global__ __launch_bounds__(256) void k_deg(const int* __restrict__ dst, int* __restrict__ deg, int E){
    int e = blockIdx.x * blockDim.x + threadIdx.x;
    if (e < E) atomicAdd(&deg[dst[e]], 1);
}

__global__ __launch_bounds__(256) void k_invdeg(const int* __restrict__ deg, float* __restrict__ invdeg, int N){
    int n = blockIdx.x * blockDim.x + threadIdx.x;
    if (n < N) invdeg[n] = 1.0f / (float)max(deg[n], 1);
}

// ---------------- exclusive scan of deg -> offs (3-kernel) ----------------
#define SCAN_B 512
__global__ __launch_bounds__(SCAN_B) void k_scan1(const int* __restrict__ deg, int* __restrict__ bsum, int N){
    __shared__ int s[SCAN_B];
    int i = blockIdx.x * SCAN_B + threadIdx.x;
    s[threadIdx.x] = (i < N) ? deg[i] : 0;
    __syncthreads();
    for (int st = SCAN_B / 2; st > 0; st >>= 1){
        if (threadIdx.x < st) s[threadIdx.x] += s[threadIdx.x + st];
        __syncthreads();
    }
    if (threadIdx.x == 0) bsum[blockIdx.x] = s[0];
}

__global__ __launch_bounds__(SCAN_B) void k_scan2(int* __restrict__ bsum, int nb){
    __shared__ int s[SCAN_B];
    int t = threadIdx.x;
    int v = (t < nb) ? bsum[t] : 0;
    s[t] = v; __syncthreads();
    for (int st = 1; st < SCAN_B; st <<= 1){
        int u = (t >= st) ? s[t - st] : 0;
        __syncthreads();
        s[t] += u;
        __syncthreads();
    }
    if (t < nb) bsum[t] = s[t] - v;   // exclusive
}

__global__ __launch_bounds__(SCAN_B) void k_scan3(const int* __restrict__ deg, const int* __restrict__ bsum,
                                                  int* __restrict__ offs, int N, int E){
    __shared__ int s[SCAN_B];
    int i = blockIdx.x * SCAN_B + threadIdx.x;
    int v = (i < N) ? deg[i] : 0;
    s[threadIdx.x] = v; __syncthreads();
    for (int st = 1; st < SCAN_B; st <<= 1){
        int u = (threadIdx.x >= st) ? s[threadIdx.x - st] : 0;
        __syncthreads();
        s[threadIdx.x] += u;
        __syncthreads();
    }
    if (i < N) offs[i] = s[threadIdx.x] - v + bsum[blockIdx.x];
    if (blockIdx.x == 0 && threadIdx.x == 0) offs[N] = E;
}

// ---------------- bucket cursor init: gcur[b] = offs[b*256] ----------------
__global__ __launch_bounds__(256) void k_bcur(const int* __restrict__ offs, int* __restrict__ gcur,
                                              int NB, int N){
    int b = blockIdx.x * blockDim.x + threadIdx.x;
    if (b < NB) gcur[b] = offs[min(b << NODE_SH, N)];
}

// ---------------- pass A: bin edges by dst-bucket with LDS reorder ----------------
// writes packed (src | dst_local<<17) into bucket-major ebuf2, bucket-ordered runs
__global__ __launch_bounds__(256) void k_binA(const int* __restrict__ src, const int* __restrict__ dst,
                                              int* __restrict__ gcur, int* __restrict__ ebuf2,
                                              int E, int NB){
    __shared__ int s_hist[NB_MAX];
    __shared__ int s_lofs[NB_MAX];
    __shared__ int s_delta[NB_MAX];
    __shared__ int s_pack[BIN_CHUNK];
    __shared__ int s_gdst[BIN_CHUNK];
    __shared__ int s_scan[256];
    const int t = threadIdx.x;
    const int e0 = blockIdx.x * BIN_CHUNK;
    for (int b = t; b < NB_MAX; b += 256) s_hist[b] = 0;
    __syncthreads();
    int my_pack[16], my_b[16], my_rank[16];
    #pragma unroll
    for (int i = 0; i < 16; ++i){
        int e = e0 + i * 256 + t;
        if (e < E){
            int s = src[e], d = dst[e];
            int b = d >> NODE_SH;
            my_pack[i] = s | ((d & 255) << 17);
            my_b[i] = b;
            my_rank[i] = atomicAdd(&s_hist[b], 1);
        } else my_b[i] = -1;
    }
    __syncthreads();
    // exclusive scan of s_hist over NB_MAX (2 entries per thread)
    int h0 = s_hist[2 * t], h1 = s_hist[2 * t + 1];
    int sum2 = h0 + h1;
    s_scan[t] = sum2;
    __syncthreads();
    for (int st = 1; st < 256; st <<= 1){
        int v = (t >= st) ? s_scan[t - st] : 0;
        __syncthreads();
        s_scan[t] += v;
        __syncthreads();
    }
    int excl = s_scan[t] - sum2;
    s_lofs[2 * t] = excl;
    s_lofs[2 * t + 1] = excl + h0;
    __syncthreads();
    // reserve disjoint global ranges per bucket
    for (int b = t; b < NB; b += 256){
        int h = s_hist[b];
        int base = (h > 0) ? atomicAdd(&gcur[b], h) : 0;
        s_delta[b] = base - s_lofs[b];
    }
    __syncthreads();
    // reorder into LDS by bucket
    #pragma unroll
    for (int i = 0; i < 16; ++i){
        if (my_b[i] >= 0){
            int j = s_lofs[my_b[i]] + my_rank[i];
            s_pack[j] = my_pack[i];
            s_gdst[j] = j + s_delta[my_b[i]];
        }
    }
    __syncthreads();
    const int cnt = min(BIN_CHUNK, E - e0);
    for (int j = t; j < cnt; j += 256)
        ebuf2[s_gdst[j]] = s_pack[j];
}

// ---------------- pass B: per-bucket CSR fill (block owns its ebuf region) ----------------
__global__ __launch_bounds__(256) void k_binB(const int* __restrict__ ebuf2, const int* __restrict__ offs,
                                              int* __restrict__ ebuf, int N){
    __shared__ int lcur[256];
    const int b = blockIdx.x, t = threadIdx.x;
    const int n0 = b << NODE_SH;
    const int n1 = min(n0 + 256, N);
    if (n0 + t < n1) lcur[t] = offs[n0 + t];
    __syncthreads();
    const int rs = offs[n0], re = offs[n1];
    for (int i = rs + t; i < re; i += 256){
        int v = ebuf2[i];
        int p = atomicAdd(&lcur[v >> 17], 1);
        ebuf[p] = v & 0x1FFFF;
    }
}

// ---------------- segment starts ----------------
__global__ __launch_bounds__(256) void k_centers(const int* __restrict__ batch, int* __restrict__ centers, int N){
    int n = blockIdx.x * blockDim.x + threadIdx.x;
    if (n < N && (n == 0 || batch[n] != batch[n - 1])) centers[batch[n]] = n;
}

// ---------------- weight prep ----------------
// WFh/WFl: MFMA B-fragments in wave-contiguous order [l][ks][fn][lane][8 shorts]
// frag element j of lane: col = fn*16 + (lane&15), k = ks*32 + (lane>>4)*8 + j
__global__ __launch_bounds__(256) void k_prepW(const float* __restrict__ Wl, const float* __restrict__ Wr,
                                               const float* __restrict__ W1, float* __restrict__ W1T,
                                               unsigned short* __restrict__ WFh, unsigned short* __restrict__ WFl){
    int i = blockIdx.x * blockDim.x + threadIdx.x;
    if (i < NL * 8 * 8 * 64){
        int lane = i & 63;
        int r = i >> 6;
        int fn = r & 7; r >>= 3;
        int ks = r & 7; r >>= 3;
        int l = r;
        int col = fn * 16 + (lane & 15);
        int k0 = ks * 32 + (lane >> 4) * 8;
        short8 hh, ll;
        #pragma unroll
        for (int j = 0; j < 8; ++j){
            int k = k0 + j;
            float w = (k < D) ? Wl[(size_t)l * D * D + col * D + k]
                              : Wr[(size_t)l * D * D + col * D + (k - D)];
            unsigned short h = f2bf_hi(w);
            hh[j] = (short)h;
            ll[j] = (short)f2bf_hi(w - bf2f(h));
        }
        *(short8*)&WFh[(size_t)i * 8] = hh;
        *(short8*)&WFl[(size_t)i * 8] = ll;
    }
    if (i < D * D){ int k = i / D, d = i % D; W1T[i] = W1[d * D + k]; }
}

// ---------------- mean aggregation (gather over CSR), 4-way ILP ----------------
__global__ __launch_bounds__(256) void k_agg(const float* __restrict__ x, const int* __restrict__ ebuf,
                                             const int* __restrict__ offs, const float* __restrict__ invdeg,
                                             float* __restrict__ agg, int N){
    int node = blockIdx.x * 8 + (threadIdx.x >> 5);
    if (node >= N) return;
    int lane = threadIdx.x & 31;
    int s = offs[node], e = offs[node + 1];
    const float4* x4 = (const float4*)x;
    float4 a0 = make_float4(0.f,0.f,0.f,0.f), a1 = a0, a2 = a0, a3 = a0;
    int i = s;
    for (; i + 4 <= e; i += 4){
        int nb0 = ebuf[i], nb1 = ebuf[i+1], nb2 = ebuf[i+2], nb3 = ebuf[i+3];
        float4 v0 = x4[(size_t)nb0 * 32 + lane];
        float4 v1 = x4[(size_t)nb1 * 32 + lane];
        float4 v2 = x4[(size_t)nb2 * 32 + lane];
        float4 v3 = x4[(size_t)nb3 * 32 + lane];
        a0.x += v0.x; a0.y += v0.y; a0.z += v0.z; a0.w += v0.w;
        a1.x += v1.x; a1.y += v1.y; a1.z += v1.z; a1.w += v1.w;
        a2.x += v2.x; a2.y += v2.y; a2.z += v2.z; a2.w += v2.w;
        a3.x += v3.x; a3.y += v3.y; a3.z += v3.z; a3.w += v3.w;
    }
    for (; i < e; ++i){
        int nb = ebuf[i];
        float4 v = x4[(size_t)nb * 32 + lane];
        a0.x += v.x; a0.y += v.y; a0.z += v.z; a0.w += v.w;
    }
    a0.x += a1.x + a2.x + a3.x;
    a0.y += a1.y + a2.y + a3.y;
    a0.z += a1.z + a2.z + a3.z;
    a0.w += a1.w + a2.w + a3.w;
    float sc = invdeg[node];
    a0.x *= sc; a0.y *= sc; a0.z *= sc; a0.w *= sc;
    ((float4*)agg)[(size_t)node * 32 + lane] = a0;
}

// ---------------- fused dense via split-bf16 MFMA, 4 row-tiles/wave ----------------
// Out[N,128] = [agg | x] (N,256) @ W (256,128) + bias, optional relu.
// Block: 256 thr (4 waves), 256 rows/block; wave w owns rows w*64..w*64+63 (4 tiles of 16).
// B-fragments loaded once per (ks,fn) as one coalesced 1KB wave load, reused by 4 tiles.
template<bool RELU>
__global__ __launch_bounds__(256) void k_dense_mfma(const float* __restrict__ Ag, const float* __restrict__ X,
                                                    const unsigned short* __restrict__ WFh,
                                                    const unsigned short* __restrict__ WFl,
                                                    const float* __restrict__ bias,
                                                    float* __restrict__ Out, int N){
    const int wave = threadIdx.x >> 6;
    const int lane = threadIdx.x & 63;
    const int l15  = lane & 15;
    const int kg   = lane >> 4;          // 0..3
    const int rbase = blockIdx.x * 256 + wave * 64;

    f32x4 acc[4][8];
    #pragma unroll
    for (int t = 0; t < 4; ++t)
        #pragma unroll
        for (int fn = 0; fn < 8; ++fn) acc[t][fn] = (f32x4){0.f, 0.f, 0.f, 0.f};

    #pragma unroll
    for (int ks = 0; ks < 8; ++ks){
        const float* S = (ks < 4) ? Ag : X;
        const int ko = (ks & 3) * 32 + kg * 8;
        short8 ah[4], al[4];
        #pragma unroll
        for (int t = 0; t < 4; ++t){
            int row = rbase + t * 16 + l15;
            row = min(row, N - 1);
            const float* ap = &S[(size_t)row * D + ko];
            float4 x0 = *(const float4*)ap;
            float4 x1 = *(const float4*)(ap + 4);
            float av[8] = {x0.x, x0.y, x0.z, x0.w, x1.x, x1.y, x1.z, x1.w};
            #pragma unroll
            for (int j = 0; j < 8; ++j){
                unsigned short h = f2bf_hi(av[j]);
                ah[t][j] = (short)h;
                al[t][j] = (short)f2bf_hi(av[j] - bf2f(h));
            }
        }
        #pragma unroll
        for (int fn = 0; fn < 8; ++fn){
            const size_t fo = ((size_t)(ks * 8 + fn) * 64 + lane) * 8;
            const short8 bh = *(const short8*)&WFh[fo];
            const short8 bl = *(const short8*)&WFl[fo];
            #pragma unroll
            for (int t = 0; t < 4; ++t){
                acc[t][fn] = __builtin_amdgcn_mfma_f32_16x16x32_bf16(ah[t], bh, acc[t][fn], 0, 0, 0);
                acc[t][fn] = __builtin_amdgcn_mfma_f32_16x16x32_bf16(al[t], bh, acc[t][fn], 0, 0, 0);
                acc[t][fn] = __builtin_amdgcn_mfma_f32_16x16x32_bf16(ah[t], bl, acc[t][fn], 0, 0, 0);
            }
        }
    }
    // epilogue: C/D layout col=lane&15, row=(lane>>4)*4+reg  [m89 verified]
    #pragma unroll
    for (int t = 0; t < 4; ++t){
        const int rb = rbase + t * 16 + (kg << 2);
        #pragma unroll
        for (int fn = 0; fn < 8; ++fn){
            const int col = fn * 16 + l15;
            const float bv = bias[col];
            #pragma unroll
            for (int r = 0; r < 4; ++r){
                const int orow = rb + r;
                if (orow < N){
                    float v = acc[t][fn][r] + bv;
                    if (RELU) v = fmaxf(v, 0.f);
                    Out[(size_t)orow * D + col] = v;
                }
            }
        }
    }
}

// ---------------- head: out[g] = W2 @ relu(W1 @ (x[c]*x[c+1]) + b1) + b2 ----------------
__global__ __launch_bounds__(128) void k_head(const float* __restrict__ x, const int* __restrict__ centers,
                                              const float* __restrict__ W1T, const float* __restrict__ b1,
                                              const float* __restrict__ W2, const float* __restrict__ b2,
                                              float* __restrict__ out){
    __shared__ float hs[D];
    __shared__ float red[D];
    int g = blockIdx.x; int d = threadIdx.x;
    int c = centers[g];
    hs[d] = x[(size_t)c * D + d] * x[(size_t)(c + 1) * D + d];
    __syncthreads();
    float acc = b1[d];
    #pragma unroll 8
    for (int k = 0; k < D; ++k) acc = fmaf(hs[k], W1T[k * D + d], acc);
    acc = fmaxf(acc, 0.f);
    red[d] = acc * W2[d];
    __syncthreads();
    for (int st = 64; st > 0; st >>= 1){
        if (d < st) red[d] += red[d + st];
        __syncthreads();
    }
    if (d == 0) out[g] = red[0] + b2[0];
}

extern "C" void kernel_launch(void* const* d_in, const int* in_sizes, int n_in,
                              void* d_out, int out_size, void* d_ws, size_t ws_size,
                              hipStream_t stream){
    const int*   z     = (const int*)  d_in[0];
    const int*   eidx  = (const int*)  d_in[1];
    const int*   batch = (const int*)  d_in[2];
    const float* zt    = (const float*)d_in[3];
    const float* Wl    = (const float*)d_in[4];
    const float* bl    = (const float*)d_in[5];
    const float* Wr    = (const float*)d_in[6];
    const float* W1    = (const float*)d_in[7];
    const float* b1    = (const float*)d_in[8];
    const float* W2    = (const float*)d_in[9];
    const float* b2    = (const float*)d_in[10];
    float* out = (float*)d_out;

    const int N = in_sizes[0];
    const int E = in_sizes[1] / 2;
    const int G = out_size;
    const int NB = (N + 255) >> NODE_SH;
    const int* src  = eidx;
    const int* dstp = eidx + E;

    char* p = (char*)d_ws;
    auto alloc = [&](size_t bytes){ char* r = p; p += align256(bytes); return r; };
    float* xa      = (float*)alloc((size_t)N * D * 4);
    float* xb      = (float*)alloc((size_t)N * D * 4);
    float* agg     = (float*)alloc((size_t)N * D * 4);
    int*   deg     = (int*)  alloc((size_t)N * 4);
    float* invdeg  = (float*)alloc((size_t)N * 4);
    int*   offs    = (int*)  alloc((size_t)(N + 1) * 4);
    int*   ebuf    = (int*)  alloc((size_t)E * 4);
    int*   ebuf2   = (int*)  alloc((size_t)E * 4);
    int*   centers = (int*)  alloc((size_t)G * 4);
    int*   bsum    = (int*)  alloc((size_t)1024 * 4);
    int*   gcur    = (int*)  alloc((size_t)NB_MAX * 4);
    float* W1T     = (float*)alloc((size_t)D * D * 4);
    unsigned short* WFh = (unsigned short*)alloc((size_t)NL * 8 * 8 * 64 * 8 * 2);
    unsigned short* WFl = (unsigned short*)alloc((size_t)NL * 8 * 8 * 64 * 8 * 2);
    (void)ws_size; (void)n_in;

    hipMemsetAsync(deg, 0, (size_t)N * 4, stream);
    k_embed<<<(N * 32 + 255) / 256, 256, 0, stream>>>(z, zt, xa, N);
    k_deg<<<(E + 255) / 256, 256, 0, stream>>>(dstp, deg, E);
    k_invdeg<<<(N + 255) / 256, 256, 0, stream>>>(deg, invdeg, N);
    int nb1 = (N + SCAN_B - 1) / SCAN_B;
    k_scan1<<<nb1, SCAN_B, 0, stream>>>(deg, bsum, N);
    k_scan2<<<1, SCAN_B, 0, stream>>>(bsum, nb1);
    k_scan3<<<nb1, SCAN_B, 0, stream>>>(deg, bsum, offs, N, E);
    k_bcur<<<(NB + 255) / 256, 256, 0, stream>>>(offs, gcur, NB, N);
    k_binA<<<(E + BIN_CHUNK - 1) / BIN_CHUNK, 256, 0, stream>>>(src, dstp, gcur, ebuf2, E, NB);
    k_binB<<<NB, 256, 0, stream>>>(ebuf2, offs, ebuf, N);
    k_centers<<<(N + 255) / 256, 256, 0, stream>>>(batch, centers, N);
    k_prepW<<<64, 256, 0, stream>>>(Wl, Wr, W1, W1T, WFh, WFl);

    float* xc = xa; float* xn = xb;
    for (int l = 0; l < NL; ++l){
        k_agg<<<(N + 7) / 8, 256, 0, stream>>>(xc, ebuf, offs, invdeg, agg, N);
        const unsigned short* wh = WFh + (size_t)l * 8 * 8 * 64 * 8;
        const unsigned short* wl = WFl + (size_t)l * 8 * 8 * 64 * 8;
        if (l < NL - 1)
            k_dense_mfma<true ><<<(N + 255) / 256, 256, 0, stream>>>(agg, xc, wh, wl, bl + l * D, xn, N);
        else
            k_dense_mfma<false><<<(N + 255) / 256, 256, 0, stream>>>(agg, xc, wh, wl, bl + l * D, xn, N);
        float* t = xc; xc = xn; xn = t;
    }
    k_head<<<G, 128, 0, stream>>>(xc, centers, W1T, b1, W2, b2, out);
}

// Round 5
// 628.356 us; speedup vs baseline: 1.5707x; 1.2199x over previous
//
#include <hip/hip_runtime.h>
#include <hip/hip_bf16.h>
#include <hip/hip_fp16.h>

#define D 128
#define NL 3
#define NODE_SH 8            // 256 nodes per bucket
#define NB_MAX 512
#define BIN_CHUNK 4096

typedef __attribute__((ext_vector_type(8))) short short8;
typedef __attribute__((ext_vector_type(4))) float f32x4;

static inline size_t align256(size_t x){ return (x + 255) & ~(size_t)255; }

static __device__ inline unsigned short f2bf_hi(float f){
    __hip_bfloat16 h = __float2bfloat16(f);          // RNE
    return *reinterpret_cast<unsigned short*>(&h);
}
static __device__ inline float bf2f(unsigned short u){
    return __uint_as_float(((unsigned)u) << 16);
}

// ---------------- embedding gather: x[n] = z_table[z[n]] (+ fp16 shadow) ----------------
__global__ __launch_bounds__(256) void k_embed(const int* __restrict__ z, const float* __restrict__ zt,
                                               float* __restrict__ x, __half* __restrict__ xh, int N){
    int i = blockIdx.x * blockDim.x + threadIdx.x;   // over N*32 float4s
    int n = i >> 5, q = i & 31;
    if (n >= N) return;
    float4 v = *(const float4*)&zt[(size_t)z[n] * D + q * 4];
    *(float4*)&x[(size_t)n * D + q * 4] = v;
    __half2 p0 = __floats2half2_rn(v.x, v.y);
    __half2 p1 = __floats2half2_rn(v.z, v.w);
    uint2 u;
    u.x = *reinterpret_cast<unsigned*>(&p0);
    u.y = *reinterpret_cast<unsigned*>(&p1);
    *(uint2*)&xh[(size_t)n * D + q * 4] = u;
}

// ---------------- degree count ----------------
__global__ __launch_bounds__(256) void k_deg(const int* __restrict__ dst, int* __restrict__ deg, int E){
    int e = blockIdx.x * blockDim.x + threadIdx.x;
    if (e < E) atomicAdd(&deg[dst[e]], 1);
}

__global__ __launch_bounds__(256) void k_invdeg(const int* __restrict__ deg, float* __restrict__ invdeg, int N){
    int n = blockIdx.x * blockDim.x + threadIdx.x;
    if (n < N) invdeg[n] = 1.0f / (float)max(deg[n], 1);
}

// ---------------- exclusive scan of deg -> offs (3-kernel) ----------------
#define SCAN_B 512
__global__ __launch_bounds__(SCAN_B) void k_scan1(const int* __restrict__ deg, int* __restrict__ bsum, int N){
    __shared__ int s[SCAN_B];
    int i = blockIdx.x * SCAN_B + threadIdx.x;
    s[threadIdx.x] = (i < N) ? deg[i] : 0;
    __syncthreads();
    for (int st = SCAN_B / 2; st > 0; st >>= 1){
        if (threadIdx.x < st) s[threadIdx.x] += s[threadIdx.x + st];
        __syncthreads();
    }
    if (threadIdx.x == 0) bsum[blockIdx.x] = s[0];
}

__global__ __launch_bounds__(SCAN_B) void k_scan2(int* __restrict__ bsum, int nb){
    __shared__ int s[SCAN_B];
    int t = threadIdx.x;
    int v = (t < nb) ? bsum[t] : 0;
    s[t] = v; __syncthreads();
    for (int st = 1; st < SCAN_B; st <<= 1){
        int u = (t >= st) ? s[t - st] : 0;
        __syncthreads();
        s[t] += u;
        __syncthreads();
    }
    if (t < nb) bsum[t] = s[t] - v;   // exclusive
}

__global__ __launch_bounds__(SCAN_B) void k_scan3(const int* __restrict__ deg, const int* __restrict__ bsum,
                                                  int* __restrict__ offs, int N, int E){
    __shared__ int s[SCAN_B];
    int i = blockIdx.x * SCAN_B + threadIdx.x;
    int v = (i < N) ? deg[i] : 0;
    s[threadIdx.x] = v; __syncthreads();
    for (int st = 1; st < SCAN_B; st <<= 1){
        int u = (threadIdx.x >= st) ? s[threadIdx.x - st] : 0;
        __syncthreads();
        s[threadIdx.x] += u;
        __syncthreads();
    }
    if (i < N) offs[i] = s[threadIdx.x] - v + bsum[blockIdx.x];
    if (blockIdx.x == 0 && threadIdx.x == 0) offs[N] = E;
}

// ---------------- bucket cursor init: gcur[b] = offs[b*256] ----------------
__global__ __launch_bounds__(256) void k_bcur(const int* __restrict__ offs, int* __restrict__ gcur,
                                              int NB, int N){
    int b = blockIdx.x * blockDim.x + threadIdx.x;
    if (b < NB) gcur[b] = offs[min(b << NODE_SH, N)];
}

// ---------------- pass A: bin edges by dst-bucket with LDS reorder ----------------
// writes packed (src | dst_local<<17) into bucket-major ebuf2, bucket-ordered runs
__global__ __launch_bounds__(256) void k_binA(const int* __restrict__ src, const int* __restrict__ dst,
                                              int* __restrict__ gcur, int* __restrict__ ebuf2,
                                              int E, int NB){
    __shared__ int s_hist[NB_MAX];
    __shared__ int s_lofs[NB_MAX];
    __shared__ int s_delta[NB_MAX];
    __shared__ int s_pack[BIN_CHUNK];
    __shared__ int s_gdst[BIN_CHUNK];
    __shared__ int s_scan[256];
    const int t = threadIdx.x;
    const int e0 = blockIdx.x * BIN_CHUNK;
    for (int b = t; b < NB_MAX; b += 256) s_hist[b] = 0;
    __syncthreads();
    int my_pack[16], my_b[16], my_rank[16];
    #pragma unroll
    for (int i = 0; i < 16; ++i){
        int e = e0 + i * 256 + t;
        if (e < E){
            int s = src[e], d = dst[e];
            int b = d >> NODE_SH;
            my_pack[i] = s | ((d & 255) << 17);
            my_b[i] = b;
            my_rank[i] = atomicAdd(&s_hist[b], 1);
        } else my_b[i] = -1;
    }
    __syncthreads();
    // exclusive scan of s_hist over NB_MAX (2 entries per thread)
    int h0 = s_hist[2 * t], h1 = s_hist[2 * t + 1];
    int sum2 = h0 + h1;
    s_scan[t] = sum2;
    __syncthreads();
    for (int st = 1; st < 256; st <<= 1){
        int v = (t >= st) ? s_scan[t - st] : 0;
        __syncthreads();
        s_scan[t] += v;
        __syncthreads();
    }
    int excl = s_scan[t] - sum2;
    s_lofs[2 * t] = excl;
    s_lofs[2 * t + 1] = excl + h0;
    __syncthreads();
    // reserve disjoint global ranges per bucket
    for (int b = t; b < NB; b += 256){
        int h = s_hist[b];
        int base = (h > 0) ? atomicAdd(&gcur[b], h) : 0;
        s_delta[b] = base - s_lofs[b];
    }
    __syncthreads();
    // reorder into LDS by bucket
    #pragma unroll
    for (int i = 0; i < 16; ++i){
        if (my_b[i] >= 0){
            int j = s_lofs[my_b[i]] + my_rank[i];
            s_pack[j] = my_pack[i];
            s_gdst[j] = j + s_delta[my_b[i]];
        }
    }
    __syncthreads();
    const int cnt = min(BIN_CHUNK, E - e0);
    for (int j = t; j < cnt; j += 256)
        ebuf2[s_gdst[j]] = s_pack[j];
}

// ---------------- pass B: per-bucket CSR fill (block owns its ebuf region) ----------------
__global__ __launch_bounds__(256) void k_binB(const int* __restrict__ ebuf2, const int* __restrict__ offs,
                                              int* __restrict__ ebuf, int N){
    __shared__ int lcur[256];
    const int b = blockIdx.x, t = threadIdx.x;
    const int n0 = b << NODE_SH;
    const int n1 = min(n0 + 256, N);
    if (n0 + t < n1) lcur[t] = offs[n0 + t];
    __syncthreads();
    const int rs = offs[n0], re = offs[n1];
    for (int i = rs + t; i < re; i += 256){
        int v = ebuf2[i];
        int p = atomicAdd(&lcur[v >> 17], 1);
        ebuf[p] = v & 0x1FFFF;
    }
}

// ---------------- segment starts ----------------
__global__ __launch_bounds__(256) void k_centers(const int* __restrict__ batch, int* __restrict__ centers, int N){
    int n = blockIdx.x * blockDim.x + threadIdx.x;
    if (n < N && (n == 0 || batch[n] != batch[n - 1])) centers[batch[n]] = n;
}

// ---------------- weight prep ----------------
// WFh/WFl: MFMA B-fragments in wave-contiguous order [l][ks][fn][lane][8 shorts]
// frag element j of lane: col = fn*16 + (lane&15), k = ks*32 + (lane>>4)*8 + j
__global__ __launch_bounds__(256) void k_prepW(const float* __restrict__ Wl, const float* __restrict__ Wr,
                                               const float* __restrict__ W1, float* __restrict__ W1T,
                                               unsigned short* __restrict__ WFh, unsigned short* __restrict__ WFl){
    int i = blockIdx.x * blockDim.x + threadIdx.x;
    if (i < NL * 8 * 8 * 64){
        int lane = i & 63;
        int r = i >> 6;
        int fn = r & 7; r >>= 3;
        int ks = r & 7; r >>= 3;
        int l = r;
        int col = fn * 16 + (lane & 15);
        int k0 = ks * 32 + (lane >> 4) * 8;
        short8 hh, ll;
        #pragma unroll
        for (int j = 0; j < 8; ++j){
            int k = k0 + j;
            float w = (k < D) ? Wl[(size_t)l * D * D + col * D + k]
                              : Wr[(size_t)l * D * D + col * D + (k - D)];
            unsigned short h = f2bf_hi(w);
            hh[j] = (short)h;
            ll[j] = (short)f2bf_hi(w - bf2f(h));
        }
        *(short8*)&WFh[(size_t)i * 8] = hh;
        *(short8*)&WFl[(size_t)i * 8] = ll;
    }
    if (i < D * D){ int k = i / D, d = i % D; W1T[i] = W1[d * D + k]; }
}

// ---------------- mean aggregation: gather fp16 rows, fp32 accumulate, 4-way ILP ----------
static __device__ inline void acc_h4(float4& a, uint2 u){
    __half2 h0 = *reinterpret_cast<__half2*>(&u.x);
    __half2 h1 = *reinterpret_cast<__half2*>(&u.y);
    float2 f0 = __half22float2(h0);
    float2 f1 = __half22float2(h1);
    a.x += f0.x; a.y += f0.y; a.z += f1.x; a.w += f1.y;
}

__global__ __launch_bounds__(256) void k_agg(const __half* __restrict__ xh, const int* __restrict__ ebuf,
                                             const int* __restrict__ offs, const float* __restrict__ invdeg,
                                             float* __restrict__ agg, int N){
    int node = blockIdx.x * 8 + (threadIdx.x >> 5);
    if (node >= N) return;
    int lane = threadIdx.x & 31;
    int s = offs[node], e = offs[node + 1];
    float4 a0 = make_float4(0.f,0.f,0.f,0.f), a1 = a0, a2 = a0, a3 = a0;
    int i = s;
    for (; i + 4 <= e; i += 4){
        int nb0 = ebuf[i], nb1 = ebuf[i+1], nb2 = ebuf[i+2], nb3 = ebuf[i+3];
        uint2 u0 = *(const uint2*)&xh[(size_t)nb0 * D + lane * 4];
        uint2 u1 = *(const uint2*)&xh[(size_t)nb1 * D + lane * 4];
        uint2 u2 = *(const uint2*)&xh[(size_t)nb2 * D + lane * 4];
        uint2 u3 = *(const uint2*)&xh[(size_t)nb3 * D + lane * 4];
        acc_h4(a0, u0); acc_h4(a1, u1); acc_h4(a2, u2); acc_h4(a3, u3);
    }
    for (; i < e; ++i){
        uint2 u = *(const uint2*)&xh[(size_t)ebuf[i] * D + lane * 4];
        acc_h4(a0, u);
    }
    a0.x += a1.x + a2.x + a3.x;
    a0.y += a1.y + a2.y + a3.y;
    a0.z += a1.z + a2.z + a3.z;
    a0.w += a1.w + a2.w + a3.w;
    float sc = invdeg[node];
    a0.x *= sc; a0.y *= sc; a0.z *= sc; a0.w *= sc;
    // agg row layout: lane covers elems [lane*4, lane*4+4)
    *(float4*)&agg[(size_t)node * D + lane * 4] = a0;
}

// ---------------- fused dense via split-bf16 MFMA, 4 row-tiles/wave ----------------
// Out[N,128] = [agg | x] (N,256) @ W (256,128) + bias, optional relu; also writes fp16 shadow.
template<bool RELU>
__global__ __launch_bounds__(256) void k_dense_mfma(const float* __restrict__ Ag, const float* __restrict__ X,
                                                    const unsigned short* __restrict__ WFh,
                                                    const unsigned short* __restrict__ WFl,
                                                    const float* __restrict__ bias,
                                                    float* __restrict__ Out, __half* __restrict__ XhOut, int N){
    const int wave = threadIdx.x >> 6;
    const int lane = threadIdx.x & 63;
    const int l15  = lane & 15;
    const int kg   = lane >> 4;          // 0..3
    const int rbase = blockIdx.x * 256 + wave * 64;

    f32x4 acc[4][8];
    #pragma unroll
    for (int t = 0; t < 4; ++t)
        #pragma unroll
        for (int fn = 0; fn < 8; ++fn) acc[t][fn] = (f32x4){0.f, 0.f, 0.f, 0.f};

    #pragma unroll
    for (int ks = 0; ks < 8; ++ks){
        const float* S = (ks < 4) ? Ag : X;
        const int ko = (ks & 3) * 32 + kg * 8;
        short8 ah[4], al[4];
        #pragma unroll
        for (int t = 0; t < 4; ++t){
            int row = rbase + t * 16 + l15;
            row = min(row, N - 1);
            const float* ap = &S[(size_t)row * D + ko];
            float4 x0 = *(const float4*)ap;
            float4 x1 = *(const float4*)(ap + 4);
            float av[8] = {x0.x, x0.y, x0.z, x0.w, x1.x, x1.y, x1.z, x1.w};
            #pragma unroll
            for (int j = 0; j < 8; ++j){
                unsigned short h = f2bf_hi(av[j]);
                ah[t][j] = (short)h;
                al[t][j] = (short)f2bf_hi(av[j] - bf2f(h));
            }
        }
        #pragma unroll
        for (int fn = 0; fn < 8; ++fn){
            const size_t fo = ((size_t)(ks * 8 + fn) * 64 + lane) * 8;
            const short8 bh = *(const short8*)&WFh[fo];
            const short8 bl = *(const short8*)&WFl[fo];
            #pragma unroll
            for (int t = 0; t < 4; ++t){
                acc[t][fn] = __builtin_amdgcn_mfma_f32_16x16x32_bf16(ah[t], bh, acc[t][fn], 0, 0, 0);
                acc[t][fn] = __builtin_amdgcn_mfma_f32_16x16x32_bf16(al[t], bh, acc[t][fn], 0, 0, 0);
                acc[t][fn] = __builtin_amdgcn_mfma_f32_16x16x32_bf16(ah[t], bl, acc[t][fn], 0, 0, 0);
            }
        }
    }
    // epilogue: C/D layout col=lane&15, row=(lane>>4)*4+reg  [m89 verified]
    #pragma unroll
    for (int t = 0; t < 4; ++t){
        const int rb = rbase + t * 16 + (kg << 2);
        #pragma unroll
        for (int fn = 0; fn < 8; ++fn){
            const int col = fn * 16 + l15;
            const float bv = bias[col];
            #pragma unroll
            for (int r = 0; r < 4; ++r){
                const int orow = rb + r;
                if (orow < N){
                    float v = acc[t][fn][r] + bv;
                    if (RELU) v = fmaxf(v, 0.f);
                    Out[(size_t)orow * D + col] = v;
                    XhOut[(size_t)orow * D + col] = __float2half(v);
                }
            }
        }
    }
}

// ---------------- head: out[g] = W2 @ relu(W1 @ (x[c]*x[c+1]) + b1) + b2 ----------------
__global__ __launch_bounds__(128) void k_head(const float* __restrict__ x, const int* __restrict__ centers,
                                              const float* __restrict__ W1T, const float* __restrict__ b1,
                                              const float* __restrict__ W2, const float* __restrict__ b2,
                                              float* __restrict__ out){
    __shared__ float hs[D];
    __shared__ float red[D];
    int g = blockIdx.x; int d = threadIdx.x;
    int c = centers[g];
    hs[d] = x[(size_t)c * D + d] * x[(size_t)(c + 1) * D + d];
    __syncthreads();
    float acc = b1[d];
    #pragma unroll 8
    for (int k = 0; k < D; ++k) acc = fmaf(hs[k], W1T[k * D + d], acc);
    acc = fmaxf(acc, 0.f);
    red[d] = acc * W2[d];
    __syncthreads();
    for (int st = 64; st > 0; st >>= 1){
        if (d < st) red[d] += red[d + st];
        __syncthreads();
    }
    if (d == 0) out[g] = red[0] + b2[0];
}

extern "C" void kernel_launch(void* const* d_in, const int* in_sizes, int n_in,
                              void* d_out, int out_size, void* d_ws, size_t ws_size,
                              hipStream_t stream){
    const int*   z     = (const int*)  d_in[0];
    const int*   eidx  = (const int*)  d_in[1];
    const int*   batch = (const int*)  d_in[2];
    const float* zt    = (const float*)d_in[3];
    const float* Wl    = (const float*)d_in[4];
    const float* bl    = (const float*)d_in[5];
    const float* Wr    = (const float*)d_in[6];
    const float* W1    = (const float*)d_in[7];
    const float* b1    = (const float*)d_in[8];
    const float* W2    = (const float*)d_in[9];
    const float* b2    = (const float*)d_in[10];
    float* out = (float*)d_out;

    const int N = in_sizes[0];
    const int E = in_sizes[1] / 2;
    const int G = out_size;
    const int NB = (N + 255) >> NODE_SH;
    const int* src  = eidx;
    const int* dstp = eidx + E;

    char* p = (char*)d_ws;
    auto alloc = [&](size_t bytes){ char* r = p; p += align256(bytes); return r; };
    float* xa      = (float*)alloc((size_t)N * D * 4);
    float* xb      = (float*)alloc((size_t)N * D * 4);
    float* agg     = (float*)alloc((size_t)N * D * 4);
    __half* xha    = (__half*)alloc((size_t)N * D * 2);
    __half* xhb    = (__half*)alloc((size_t)N * D * 2);
    int*   deg     = (int*)  alloc((size_t)N * 4);
    float* invdeg  = (float*)alloc((size_t)N * 4);
    int*   offs    = (int*)  alloc((size_t)(N + 1) * 4);
    int*   ebuf    = (int*)  alloc((size_t)E * 4);
    int*   ebuf2   = (int*)  alloc((size_t)E * 4);
    int*   centers = (int*)  alloc((size_t)G * 4);
    int*   bsum    = (int*)  alloc((size_t)1024 * 4);
    int*   gcur    = (int*)  alloc((size_t)NB_MAX * 4);
    float* W1T     = (float*)alloc((size_t)D * D * 4);
    unsigned short* WFh = (unsigned short*)alloc((size_t)NL * 8 * 8 * 64 * 8 * 2);
    unsigned short* WFl = (unsigned short*)alloc((size_t)NL * 8 * 8 * 64 * 8 * 2);
    (void)ws_size; (void)n_in;

    hipMemsetAsync(deg, 0, (size_t)N * 4, stream);
    k_embed<<<(N * 32 + 255) / 256, 256, 0, stream>>>(z, zt, xa, xha, N);
    k_deg<<<(E + 255) / 256, 256, 0, stream>>>(dstp, deg, E);
    k_invdeg<<<(N + 255) / 256, 256, 0, stream>>>(deg, invdeg, N);
    int nb1 = (N + SCAN_B - 1) / SCAN_B;
    k_scan1<<<nb1, SCAN_B, 0, stream>>>(deg, bsum, N);
    k_scan2<<<1, SCAN_B, 0, stream>>>(bsum, nb1);
    k_scan3<<<nb1, SCAN_B, 0, stream>>>(deg, bsum, offs, N, E);
    k_bcur<<<(NB + 255) / 256, 256, 0, stream>>>(offs, gcur, NB, N);
    k_binA<<<(E + BIN_CHUNK - 1) / BIN_CHUNK, 256, 0, stream>>>(src, dstp, gcur, ebuf2, E, NB);
    k_binB<<<NB, 256, 0, stream>>>(ebuf2, offs, ebuf, N);
    k_centers<<<(N + 255) / 256, 256, 0, stream>>>(batch, centers, N);
    k_prepW<<<64, 256, 0, stream>>>(Wl, Wr, W1, W1T, WFh, WFl);

    float* xc = xa; float* xn = xb;
    __half* xhc = xha; __half* xhn = xhb;
    for (int l = 0; l < NL; ++l){
        k_agg<<<(N + 7) / 8, 256, 0, stream>>>(xhc, ebuf, offs, invdeg, agg, N);
        const unsigned short* wh = WFh + (size_t)l * 8 * 8 * 64 * 8;
        const unsigned short* wl = WFl + (size_t)l * 8 * 8 * 64 * 8;
        if (l < NL - 1)
            k_dense_mfma<true ><<<(N + 255) / 256, 256, 0, stream>>>(agg, xc, wh, wl, bl + l * D, xn, xhn, N);
        else
            k_dense_mfma<false><<<(N + 255) / 256, 256, 0, stream>>>(agg, xc, wh, wl, bl + l * D, xn, xhn, N);
        float* t = xc; xc = xn; xn = t;
        __half* th = xhc; xhc = xhn; xhn = th;
    }
    k_head<<<G, 128, 0, stream>>>(xc, centers, W1T, b1, W2, b2, out);
}

// Round 7
// 551.196 us; speedup vs baseline: 1.7906x; 1.1400x over previous
//
#include <hip/hip_runtime.h>
#include <hip/hip_bf16.h>
#include <hip/hip_fp16.h>

#define D 128
#define NL 3
#define NODE_SH 8            // 256 nodes per bucket
#define NB_MAX 512
#define BIN_CHUNK 4096

typedef __attribute__((ext_vector_type(8))) short short8;
typedef __attribute__((ext_vector_type(4))) float f32x4;

static inline size_t align256(size_t x){ return (x + 255) & ~(size_t)255; }

static __device__ inline unsigned short f2bf_hi(float f){
    __hip_bfloat16 h = __float2bfloat16(f);          // RNE
    return *reinterpret_cast<unsigned short*>(&h);
}
static __device__ inline float bf2f(unsigned short u){
    return __uint_as_float(((unsigned)u) << 16);
}

// ---------------- embedding gather: x[n] = z_table[z[n]] (+ fp16 shadow) ----------------
__global__ __launch_bounds__(256) void k_embed(const int* __restrict__ z, const float* __restrict__ zt,
                                               float* __restrict__ x, __half* __restrict__ xh, int N){
    int i = blockIdx.x * blockDim.x + threadIdx.x;   // over N*32 float4s
    int n = i >> 5, q = i & 31;
    if (n >= N) return;
    float4 v = *(const float4*)&zt[(size_t)z[n] * D + q * 4];
    *(float4*)&x[(size_t)n * D + q * 4] = v;
    __half2 p0 = __floats2half2_rn(v.x, v.y);
    __half2 p1 = __floats2half2_rn(v.z, v.w);
    uint2 u;
    u.x = *reinterpret_cast<unsigned*>(&p0);
    u.y = *reinterpret_cast<unsigned*>(&p1);
    *(uint2*)&xh[(size_t)n * D + q * 4] = u;
}

// ---------------- degree count ----------------
__global__ __launch_bounds__(256) void k_deg(const int* __restrict__ dst, int* __restrict__ deg, int E){
    int e = blockIdx.x * blockDim.x + threadIdx.x;
    if (e < E) atomicAdd(&deg[dst[e]], 1);
}

__global__ __launch_bounds__(256) void k_invdeg(const int* __restrict__ deg, float* __restrict__ invdeg, int N){
    int n = blockIdx.x * blockDim.x + threadIdx.x;
    if (n < N) invdeg[n] = 1.0f / (float)max(deg[n], 1);
}

// ---------------- exclusive scan of deg -> offs (3-kernel) ----------------
#define SCAN_B 512
__global__ __launch_bounds__(SCAN_B) void k_scan1(const int* __restrict__ deg, int* __restrict__ bsum, int N){
    __shared__ int s[SCAN_B];
    int i = blockIdx.x * SCAN_B + threadIdx.x;
    s[threadIdx.x] = (i < N) ? deg[i] : 0;
    __syncthreads();
    for (int st = SCAN_B / 2; st > 0; st >>= 1){
        if (threadIdx.x < st) s[threadIdx.x] += s[threadIdx.x + st];
        __syncthreads();
    }
    if (threadIdx.x == 0) bsum[blockIdx.x] = s[0];
}

__global__ __launch_bounds__(SCAN_B) void k_scan2(int* __restrict__ bsum, int nb){
    __shared__ int s[SCAN_B];
    int t = threadIdx.x;
    int v = (t < nb) ? bsum[t] : 0;
    s[t] = v; __syncthreads();
    for (int st = 1; st < SCAN_B; st <<= 1){
        int u = (t >= st) ? s[t - st] : 0;
        __syncthreads();
        s[t] += u;
        __syncthreads();
    }
    if (t < nb) bsum[t] = s[t] - v;   // exclusive
}

__global__ __launch_bounds__(SCAN_B) void k_scan3(const int* __restrict__ deg, const int* __restrict__ bsum,
                                                  int* __restrict__ offs, int N, int E){
    __shared__ int s[SCAN_B];
    int i = blockIdx.x * SCAN_B + threadIdx.x;
    int v = (i < N) ? deg[i] : 0;
    s[threadIdx.x] = v; __syncthreads();
    for (int st = 1; st < SCAN_B; st <<= 1){
        int u = (threadIdx.x >= st) ? s[threadIdx.x - st] : 0;
        __syncthreads();
        s[threadIdx.x] += u;
        __syncthreads();
    }
    if (i < N) offs[i] = s[threadIdx.x] - v + bsum[blockIdx.x];
    if (blockIdx.x == 0 && threadIdx.x == 0) offs[N] = E;
}

// ---------------- bucket cursor init: gcur[b] = offs[b*256] ----------------
__global__ __launch_bounds__(256) void k_bcur(const int* __restrict__ offs, int* __restrict__ gcur,
                                              int NB, int N){
    int b = blockIdx.x * blockDim.x + threadIdx.x;
    if (b < NB) gcur[b] = offs[min(b << NODE_SH, N)];
}

// ---------------- pass A: bin edges by dst-bucket with LDS reorder ----------------
// writes packed (src | dst_local<<17) into bucket-major ebuf2, bucket-ordered runs
__global__ __launch_bounds__(256) void k_binA(const int* __restrict__ src, const int* __restrict__ dst,
                                              int* __restrict__ gcur, int* __restrict__ ebuf2,
                                              int E, int NB){
    __shared__ int s_hist[NB_MAX];
    __shared__ int s_lofs[NB_MAX];
    __shared__ int s_delta[NB_MAX];
    __shared__ int s_pack[BIN_CHUNK];
    __shared__ int s_gdst[BIN_CHUNK];
    __shared__ int s_scan[256];
    const int t = threadIdx.x;
    const int e0 = blockIdx.x * BIN_CHUNK;
    for (int b = t; b < NB_MAX; b += 256) s_hist[b] = 0;
    __syncthreads();
    int my_pack[16], my_b[16], my_rank[16];
    #pragma unroll
    for (int i = 0; i < 16; ++i){
        int e = e0 + i * 256 + t;
        if (e < E){
            int s = src[e], d = dst[e];
            int b = d >> NODE_SH;
            my_pack[i] = s | ((d & 255) << 17);
            my_b[i] = b;
            my_rank[i] = atomicAdd(&s_hist[b], 1);
        } else my_b[i] = -1;
    }
    __syncthreads();
    // exclusive scan of s_hist over NB_MAX (2 entries per thread)
    int h0 = s_hist[2 * t], h1 = s_hist[2 * t + 1];
    int sum2 = h0 + h1;
    s_scan[t] = sum2;
    __syncthreads();
    for (int st = 1; st < 256; st <<= 1){
        int v = (t >= st) ? s_scan[t - st] : 0;
        __syncthreads();
        s_scan[t] += v;
        __syncthreads();
    }
    int excl = s_scan[t] - sum2;
    s_lofs[2 * t] = excl;
    s_lofs[2 * t + 1] = excl + h0;
    __syncthreads();
    // reserve disjoint global ranges per bucket
    for (int b = t; b < NB; b += 256){
        int h = s_hist[b];
        int base = (h > 0) ? atomicAdd(&gcur[b], h) : 0;
        s_delta[b] = base - s_lofs[b];
    }
    __syncthreads();
    // reorder into LDS by bucket
    #pragma unroll
    for (int i = 0; i < 16; ++i){
        if (my_b[i] >= 0){
            int j = s_lofs[my_b[i]] + my_rank[i];
            s_pack[j] = my_pack[i];
            s_gdst[j] = j + s_delta[my_b[i]];
        }
    }
    __syncthreads();
    const int cnt = min(BIN_CHUNK, E - e0);
    for (int j = t; j < cnt; j += 256)
        ebuf2[s_gdst[j]] = s_pack[j];
}

// ---------------- pass B: per-bucket CSR fill (block owns its ebuf region) ----------------
__global__ __launch_bounds__(256) void k_binB(const int* __restrict__ ebuf2, const int* __restrict__ offs,
                                              int* __restrict__ ebuf, int N){
    __shared__ int lcur[256];
    const int b = blockIdx.x, t = threadIdx.x;
    const int n0 = b << NODE_SH;
    const int n1 = min(n0 + 256, N);
    if (n0 + t < n1) lcur[t] = offs[n0 + t];
    __syncthreads();
    const int rs = offs[n0], re = offs[n1];
    for (int i = rs + t; i < re; i += 256){
        int v = ebuf2[i];
        int p = atomicAdd(&lcur[v >> 17], 1);
        ebuf[p] = v & 0x1FFFF;
    }
}

// ---------------- segment starts ----------------
__global__ __launch_bounds__(256) void k_centers(const int* __restrict__ batch, int* __restrict__ centers, int N){
    int n = blockIdx.x * blockDim.x + threadIdx.x;
    if (n < N && (n == 0 || batch[n] != batch[n - 1])) centers[batch[n]] = n;
}

// ---------------- weight prep ----------------
// WFh/WFl: MFMA B-fragments in wave-contiguous order [l][ks][fn][lane][8 shorts]
// frag element j of lane: col = fn*16 + (lane&15), k = ks*32 + (lane>>4)*8 + j
__global__ __launch_bounds__(256) void k_prepW(const float* __restrict__ Wl, const float* __restrict__ Wr,
                                               const float* __restrict__ W1, float* __restrict__ W1T,
                                               unsigned short* __restrict__ WFh, unsigned short* __restrict__ WFl){
    int i = blockIdx.x * blockDim.x + threadIdx.x;
    if (i < NL * 8 * 8 * 64){
        int lane = i & 63;
        int r = i >> 6;
        int fn = r & 7; r >>= 3;
        int ks = r & 7; r >>= 3;
        int l = r;
        int col = fn * 16 + (lane & 15);
        int k0 = ks * 32 + (lane >> 4) * 8;
        short8 hh, ll;
        #pragma unroll
        for (int j = 0; j < 8; ++j){
            int k = k0 + j;
            float w = (k < D) ? Wl[(size_t)l * D * D + col * D + k]
                              : Wr[(size_t)l * D * D + col * D + (k - D)];
            unsigned short h = f2bf_hi(w);
            hh[j] = (short)h;
            ll[j] = (short)f2bf_hi(w - bf2f(h));
        }
        *(short8*)&WFh[(size_t)i * 8] = hh;
        *(short8*)&WFl[(size_t)i * 8] = ll;
    }
    if (i < D * D){ int k = i / D, d = i % D; W1T[i] = W1[d * D + k]; }
}

// ---------------- mean aggregation: gather fp16 rows, fp32 accumulate, 4-way ILP ----------
static __device__ inline void acc_h4(float4& a, uint2 u){
    __half2 h0 = *reinterpret_cast<__half2*>(&u.x);
    __half2 h1 = *reinterpret_cast<__half2*>(&u.y);
    float2 f0 = __half22float2(h0);
    float2 f1 = __half22float2(h1);
    a.x += f0.x; a.y += f0.y; a.z += f1.x; a.w += f1.y;
}

__global__ __launch_bounds__(256) void k_agg(const __half* __restrict__ xh, const int* __restrict__ ebuf,
                                             const int* __restrict__ offs, const float* __restrict__ invdeg,
                                             float* __restrict__ agg, int N){
    int node = blockIdx.x * 8 + (threadIdx.x >> 5);
    if (node >= N) return;
    int lane = threadIdx.x & 31;
    int s = offs[node], e = offs[node + 1];
    float4 a0 = make_float4(0.f,0.f,0.f,0.f), a1 = a0, a2 = a0, a3 = a0;
    int i = s;
    for (; i + 4 <= e; i += 4){
        int nb0 = ebuf[i], nb1 = ebuf[i+1], nb2 = ebuf[i+2], nb3 = ebuf[i+3];
        uint2 u0 = *(const uint2*)&xh[(size_t)nb0 * D + lane * 4];
        uint2 u1 = *(const uint2*)&xh[(size_t)nb1 * D + lane * 4];
        uint2 u2 = *(const uint2*)&xh[(size_t)nb2 * D + lane * 4];
        uint2 u3 = *(const uint2*)&xh[(size_t)nb3 * D + lane * 4];
        acc_h4(a0, u0); acc_h4(a1, u1); acc_h4(a2, u2); acc_h4(a3, u3);
    }
    for (; i < e; ++i){
        uint2 u = *(const uint2*)&xh[(size_t)ebuf[i] * D + lane * 4];
        acc_h4(a0, u);
    }
    a0.x += a1.x + a2.x + a3.x;
    a0.y += a1.y + a2.y + a3.y;
    a0.z += a1.z + a2.z + a3.z;
    a0.w += a1.w + a2.w + a3.w;
    float sc = invdeg[node];
    a0.x *= sc; a0.y *= sc; a0.z *= sc; a0.w *= sc;
    // agg row layout: lane covers elems [lane*4, lane*4+4)
    *(float4*)&agg[(size_t)node * D + lane * 4] = a0;
}

// ---------------- fused dense via split-bf16 MFMA, 2 row-tiles/wave ----------------
// Out[N,128] = [agg | x] (N,256) @ W (256,128) + bias, optional relu; also writes fp16 shadow.
// Block: 256 thr (4 waves), 128 rows/block; wave w owns rows w*32..w*32+31 (2 tiles of 16).
// Round-6 change: 4->2 tiles/wave. Grid 391->782 blocks (1.5->3 waves/SIMD); B-fragment
// loads stay L1-hot (128 KB/layer, shared across the block's 4 waves).
template<bool RELU>
__global__ __launch_bounds__(256) void k_dense_mfma(const float* __restrict__ Ag, const float* __restrict__ X,
                                                    const unsigned short* __restrict__ WFh,
                                                    const unsigned short* __restrict__ WFl,
                                                    const float* __restrict__ bias,
                                                    float* __restrict__ Out, __half* __restrict__ XhOut, int N){
    const int wave = threadIdx.x >> 6;
    const int lane = threadIdx.x & 63;
    const int l15  = lane & 15;
    const int kg   = lane >> 4;          // 0..3
    const int rbase = blockIdx.x * 128 + wave * 32;

    f32x4 acc[2][8];
    #pragma unroll
    for (int t = 0; t < 2; ++t)
        #pragma unroll
        for (int fn = 0; fn < 8; ++fn) acc[t][fn] = (f32x4){0.f, 0.f, 0.f, 0.f};

    #pragma unroll
    for (int ks = 0; ks < 8; ++ks){
        const float* S = (ks < 4) ? Ag : X;
        const int ko = (ks & 3) * 32 + kg * 8;
        short8 ah[2], al[2];
        #pragma unroll
        for (int t = 0; t < 2; ++t){
            int row = rbase + t * 16 + l15;
            row = min(row, N - 1);
            const float* ap = &S[(size_t)row * D + ko];
            float4 x0 = *(const float4*)ap;
            float4 x1 = *(const float4*)(ap + 4);
            float av[8] = {x0.x, x0.y, x0.z, x0.w, x1.x, x1.y, x1.z, x1.w};
            #pragma unroll
            for (int j = 0; j < 8; ++j){
                unsigned short h = f2bf_hi(av[j]);
                ah[t][j] = (short)h;
                al[t][j] = (short)f2bf_hi(av[j] - bf2f(h));
            }
        }
        #pragma unroll
        for (int fn = 0; fn < 8; ++fn){
            const size_t fo = ((size_t)(ks * 8 + fn) * 64 + lane) * 8;
            const short8 bh = *(const short8*)&WFh[fo];
            const short8 bl = *(const short8*)&WFl[fo];
            #pragma unroll
            for (int t = 0; t < 2; ++t){
                acc[t][fn] = __builtin_amdgcn_mfma_f32_16x16x32_bf16(ah[t], bh, acc[t][fn], 0, 0, 0);
                acc[t][fn] = __builtin_amdgcn_mfma_f32_16x16x32_bf16(al[t], bh, acc[t][fn], 0, 0, 0);
                acc[t][fn] = __builtin_amdgcn_mfma_f32_16x16x32_bf16(ah[t], bl, acc[t][fn], 0, 0, 0);
            }
        }
    }
    // epilogue: C/D layout col=lane&15, row=(lane>>4)*4+reg  [m89 verified]
    #pragma unroll
    for (int t = 0; t < 2; ++t){
        const int rb = rbase + t * 16 + (kg << 2);
        #pragma unroll
        for (int fn = 0; fn < 8; ++fn){
            const int col = fn * 16 + l15;
            const float bv = bias[col];
            #pragma unroll
            for (int r = 0; r < 4; ++r){
                const int orow = rb + r;
                if (orow < N){
                    float v = acc[t][fn][r] + bv;
                    if (RELU) v = fmaxf(v, 0.f);
                    Out[(size_t)orow * D + col] = v;
                    XhOut[(size_t)orow * D + col] = __float2half(v);
                }
            }
        }
    }
}

// ---------------- head: out[g] = W2 @ relu(W1 @ (x[c]*x[c+1]) + b1) + b2 ----------------
__global__ __launch_bounds__(128) void k_head(const float* __restrict__ x, const int* __restrict__ centers,
                                              const float* __restrict__ W1T, const float* __restrict__ b1,
                                              const float* __restrict__ W2, const float* __restrict__ b2,
                                              float* __restrict__ out){
    __shared__ float hs[D];
    __shared__ float red[D];
    int g = blockIdx.x; int d = threadIdx.x;
    int c = centers[g];
    hs[d] = x[(size_t)c * D + d] * x[(size_t)(c + 1) * D + d];
    __syncthreads();
    float acc = b1[d];
    #pragma unroll 8
    for (int k = 0; k < D; ++k) acc = fmaf(hs[k], W1T[k * D + d], acc);
    acc = fmaxf(acc, 0.f);
    red[d] = acc * W2[d];
    __syncthreads();
    for (int st = 64; st > 0; st >>= 1){
        if (d < st) red[d] += red[d + st];
        __syncthreads();
    }
    if (d == 0) out[g] = red[0] + b2[0];
}

extern "C" void kernel_launch(void* const* d_in, const int* in_sizes, int n_in,
                              void* d_out, int out_size, void* d_ws, size_t ws_size,
                              hipStream_t stream){
    const int*   z     = (const int*)  d_in[0];
    const int*   eidx  = (const int*)  d_in[1];
    const int*   batch = (const int*)  d_in[2];
    const float* zt    = (const float*)d_in[3];
    const float* Wl    = (const float*)d_in[4];
    const float* bl    = (const float*)d_in[5];
    const float* Wr    = (const float*)d_in[6];
    const float* W1    = (const float*)d_in[7];
    const float* b1    = (const float*)d_in[8];
    const float* W2    = (const float*)d_in[9];
    const float* b2    = (const float*)d_in[10];
    float* out = (float*)d_out;

    const int N = in_sizes[0];
    const int E = in_sizes[1] / 2;
    const int G = out_size;
    const int NB = (N + 255) >> NODE_SH;
    const int* src  = eidx;
    const int* dstp = eidx + E;

    char* p = (char*)d_ws;
    auto alloc = [&](size_t bytes){ char* r = p; p += align256(bytes); return r; };
    float* xa      = (float*)alloc((size_t)N * D * 4);
    float* xb      = (float*)alloc((size_t)N * D * 4);
    float* agg     = (float*)alloc((size_t)N * D * 4);
    __half* xha    = (__half*)alloc((size_t)N * D * 2);
    __half* xhb    = (__half*)alloc((size_t)N * D * 2);
    int*   deg     = (int*)  alloc((size_t)N * 4);
    float* invdeg  = (float*)alloc((size_t)N * 4);
    int*   offs    = (int*)  alloc((size_t)(N + 1) * 4);
    int*   ebuf    = (int*)  alloc((size_t)E * 4);
    int*   ebuf2   = (int*)  alloc((size_t)E * 4);
    int*   centers = (int*)  alloc((size_t)G * 4);
    int*   bsum    = (int*)  alloc((size_t)1024 * 4);
    int*   gcur    = (int*)  alloc((size_t)NB_MAX * 4);
    float* W1T     = (float*)alloc((size_t)D * D * 4);
    unsigned short* WFh = (unsigned short*)alloc((size_t)NL * 8 * 8 * 64 * 8 * 2);
    unsigned short* WFl = (unsigned short*)alloc((size_t)NL * 8 * 8 * 64 * 8 * 2);
    (void)ws_size; (void)n_in;

    hipMemsetAsync(deg, 0, (size_t)N * 4, stream);
    k_embed<<<(N * 32 + 255) / 256, 256, 0, stream>>>(z, zt, xa, xha, N);
    k_deg<<<(E + 255) / 256, 256, 0, stream>>>(dstp, deg, E);
    k_invdeg<<<(N + 255) / 256, 256, 0, stream>>>(deg, invdeg, N);
    int nb1 = (N + SCAN_B - 1) / SCAN_B;
    k_scan1<<<nb1, SCAN_B, 0, stream>>>(deg, bsum, N);
    k_scan2<<<1, SCAN_B, 0, stream>>>(bsum, nb1);
    k_scan3<<<nb1, SCAN_B, 0, stream>>>(deg, bsum, offs, N, E);
    k_bcur<<<(NB + 255) / 256, 256, 0, stream>>>(offs, gcur, NB, N);
    k_binA<<<(E + BIN_CHUNK - 1) / BIN_CHUNK, 256, 0, stream>>>(src, dstp, gcur, ebuf2, E, NB);
    k_binB<<<NB, 256, 0, stream>>>(ebuf2, offs, ebuf, N);
    k_centers<<<(N + 255) / 256, 256, 0, stream>>>(batch, centers, N);
    k_prepW<<<64, 256, 0, stream>>>(Wl, Wr, W1, W1T, WFh, WFl);

    float* xc = xa; float* xn = xb;
    __half* xhc = xha; __half* xhn = xhb;
    for (int l = 0; l < NL; ++l){
        k_agg<<<(N + 7) / 8, 256, 0, stream>>>(xhc, ebuf, offs, invdeg, agg, N);
        const unsigned short* wh = WFh + (size_t)l * 8 * 8 * 64 * 8;
        const unsigned short* wl = WFl + (size_t)l * 8 * 8 * 64 * 8;
        if (l < NL - 1)
            k_dense_mfma<true ><<<(N + 127) / 128, 256, 0, stream>>>(agg, xc, wh, wl, bl + l * D, xn, xhn, N);
        else
            k_dense_mfma<false><<<(N + 127) / 128, 256, 0, stream>>>(agg, xc, wh, wl, bl + l * D, xn, xhn, N);
        float* t = xc; xc = xn; xn = t;
        __half* th = xhc; xhc = xhn; xhn = th;
    }
    k_head<<<G, 128, 0, stream>>>(xc, centers, W1T, b1, W2, b2, out);
}

// Round 10
// 492.849 us; speedup vs baseline: 2.0026x; 1.1184x over previous
//
#include <hip/hip_runtime.h>
#include <hip/hip_bf16.h>
#include <hip/hip_fp16.h>

#define D 128
#define NL 3
#define NODE_SH 8            // 256 nodes per bucket
#define NB_MAX 512
#define BIN_CHUNK 4096

typedef __attribute__((ext_vector_type(8))) short short8;
typedef __attribute__((ext_vector_type(4))) float f32x4;

static inline size_t align256(size_t x){ return (x + 255) & ~(size_t)255; }

static __device__ inline unsigned short f2bf_hi(float f){
    __hip_bfloat16 h = __float2bfloat16(f);          // RNE
    return *reinterpret_cast<unsigned short*>(&h);
}
static __device__ inline float bf2f(unsigned short u){
    return __uint_as_float(((unsigned)u) << 16);
}

// ---------------- embedding gather: x[n] = z_table[z[n]] (+ fp16 shadow) ----------------
__global__ __launch_bounds__(256) void k_embed(const int* __restrict__ z, const float* __restrict__ zt,
                                               float* __restrict__ x, __half* __restrict__ xh, int N){
    int i = blockIdx.x * blockDim.x + threadIdx.x;   // over N*32 float4s
    int n = i >> 5, q = i & 31;
    if (n >= N) return;
    float4 v = *(const float4*)&zt[(size_t)z[n] * D + q * 4];
    *(float4*)&x[(size_t)n * D + q * 4] = v;
    __half2 p0 = __floats2half2_rn(v.x, v.y);
    __half2 p1 = __floats2half2_rn(v.z, v.w);
    uint2 u;
    u.x = *reinterpret_cast<unsigned*>(&p0);
    u.y = *reinterpret_cast<unsigned*>(&p1);
    *(uint2*)&xh[(size_t)n * D + q * 4] = u;
}

// ---------------- bucket-grain edge histogram (replaces k_deg) ----------------
// LDS hist over NB buckets per block, then one global atomic per (block,bucket).
__global__ __launch_bounds__(256) void k_bcount(const int* __restrict__ dst, int* __restrict__ bcnt,
                                                int E, int NB){
    __shared__ int h[NB_MAX];
    const int t = threadIdx.x;
    for (int b = t; b < NB_MAX; b += 256) h[b] = 0;
    __syncthreads();
    const int stride = gridDim.x * 256;
    for (int e = blockIdx.x * 256 + t; e < E; e += stride)
        atomicAdd(&h[dst[e] >> NODE_SH], 1);
    __syncthreads();
    for (int b = t; b < NB; b += 256){
        int v = h[b];
        if (v) atomicAdd(&bcnt[b], v);
    }
}

// ---------------- bucket scan: gbase = excl-scan(bcnt), init gcur, offs[N]=E ----------------
__global__ __launch_bounds__(512) void k_bscan(const int* __restrict__ bcnt, int* __restrict__ gbase,
                                               int* __restrict__ gcur, int* __restrict__ offs,
                                               int NB, int N, int E){
    __shared__ int s[512];
    int t = threadIdx.x;
    int v = (t < NB) ? bcnt[t] : 0;
    s[t] = v; __syncthreads();
    for (int st = 1; st < 512; st <<= 1){
        int u = (t >= st) ? s[t - st] : 0;
        __syncthreads();
        s[t] += u;
        __syncthreads();
    }
    if (t < NB){
        int base = s[t] - v;      // exclusive
        gbase[t] = base;
        gcur[t] = base;
    }
    if (t == 0){ gbase[NB] = E; offs[N] = E; }
}

// ---------------- pass A: bin edges by dst-bucket with LDS reorder ----------------
// writes packed (src | dst_local<<17) into bucket-major ebuf2, bucket-ordered runs
__global__ __launch_bounds__(256) void k_binA(const int* __restrict__ src, const int* __restrict__ dst,
                                              int* __restrict__ gcur, int* __restrict__ ebuf2,
                                              int E, int NB){
    __shared__ int s_hist[NB_MAX];
    __shared__ int s_lofs[NB_MAX];
    __shared__ int s_delta[NB_MAX];
    __shared__ int s_pack[BIN_CHUNK];
    __shared__ int s_gdst[BIN_CHUNK];
    __shared__ int s_scan[256];
    const int t = threadIdx.x;
    const int e0 = blockIdx.x * BIN_CHUNK;
    for (int b = t; b < NB_MAX; b += 256) s_hist[b] = 0;
    __syncthreads();
    int my_pack[16], my_b[16], my_rank[16];
    #pragma unroll
    for (int i = 0; i < 16; ++i){
        int e = e0 + i * 256 + t;
        if (e < E){
            int s = src[e], d = dst[e];
            int b = d >> NODE_SH;
            my_pack[i] = s | ((d & 255) << 17);
            my_b[i] = b;
            my_rank[i] = atomicAdd(&s_hist[b], 1);
        } else my_b[i] = -1;
    }
    __syncthreads();
    // exclusive scan of s_hist over NB_MAX (2 entries per thread)
    int h0 = s_hist[2 * t], h1 = s_hist[2 * t + 1];
    int sum2 = h0 + h1;
    s_scan[t] = sum2;
    __syncthreads();
    for (int st = 1; st < 256; st <<= 1){
        int v = (t >= st) ? s_scan[t - st] : 0;
        __syncthreads();
        s_scan[t] += v;
        __syncthreads();
    }
    int excl = s_scan[t] - sum2;
    s_lofs[2 * t] = excl;
    s_lofs[2 * t + 1] = excl + h0;
    __syncthreads();
    // reserve disjoint global ranges per bucket
    for (int b = t; b < NB; b += 256){
        int h = s_hist[b];
        int base = (h > 0) ? atomicAdd(&gcur[b], h) : 0;
        s_delta[b] = base - s_lofs[b];
    }
    __syncthreads();
    // reorder into LDS by bucket
    #pragma unroll
    for (int i = 0; i < 16; ++i){
        if (my_b[i] >= 0){
            int j = s_lofs[my_b[i]] + my_rank[i];
            s_pack[j] = my_pack[i];
            s_gdst[j] = j + s_delta[my_b[i]];
        }
    }
    __syncthreads();
    const int cnt = min(BIN_CHUNK, E - e0);
    for (int j = t; j < cnt; j += 256)
        ebuf2[s_gdst[j]] = s_pack[j];
}

// ---------------- pass B: per-bucket node-degree + CSR fill (fused deg/offs/invdeg) -----
// Block b owns nodes [b*256, b*256+256) and ebuf region [gbase[b], gbase[b+1]).
__global__ __launch_bounds__(256) void k_binB(const int* __restrict__ ebuf2, const int* __restrict__ gbase,
                                              int* __restrict__ ebuf, int* __restrict__ offs,
                                              float* __restrict__ invdeg, int N){
    __shared__ int cnt[256];
    __shared__ int lcur[256];
    __shared__ int s_scan[256];
    const int b = blockIdx.x, t = threadIdx.x;
    const int n0 = b << NODE_SH;
    const int rs = gbase[b], re = gbase[b + 1];
    cnt[t] = 0;
    __syncthreads();
    // per-node degree histogram (LDS atomics)
    for (int i = rs + t; i < re; i += 256)
        atomicAdd(&cnt[ebuf2[i] >> 17], 1);
    __syncthreads();
    const int c = cnt[t];
    // exclusive scan of cnt -> local offsets
    s_scan[t] = c;
    __syncthreads();
    for (int st = 1; st < 256; st <<= 1){
        int u = (t >= st) ? s_scan[t - st] : 0;
        __syncthreads();
        s_scan[t] += u;
        __syncthreads();
    }
    const int excl = s_scan[t] - c;
    lcur[t] = rs + excl;
    if (n0 + t < N){
        offs[n0 + t]   = rs + excl;
        invdeg[n0 + t] = 1.0f / (float)max(c, 1);
    }
    __syncthreads();
    // place edges (src) grouped by node
    for (int i = rs + t; i < re; i += 256){
        int v = ebuf2[i];
        int p = atomicAdd(&lcur[v >> 17], 1);
        ebuf[p] = v & 0x1FFFF;
    }
}

// ---------------- segment starts ----------------
__global__ __launch_bounds__(256) void k_centers(const int* __restrict__ batch, int* __restrict__ centers, int N){
    int n = blockIdx.x * blockDim.x + threadIdx.x;
    if (n < N && (n == 0 || batch[n] != batch[n - 1])) centers[batch[n]] = n;
}

// ---------------- weight prep ----------------
// WFh/WFl: MFMA B-fragments in wave-contiguous order [l][ks][fn][lane][8 shorts]
// frag element j of lane: col = fn*16 + (lane&15), k = ks*32 + (lane>>4)*8 + j
__global__ __launch_bounds__(256) void k_prepW(const float* __restrict__ Wl, const float* __restrict__ Wr,
                                               const float* __restrict__ W1, float* __restrict__ W1T,
                                               unsigned short* __restrict__ WFh, unsigned short* __restrict__ WFl){
    int i = blockIdx.x * blockDim.x + threadIdx.x;
    if (i < NL * 8 * 8 * 64){
        int lane = i & 63;
        int r = i >> 6;
        int fn = r & 7; r >>= 3;
        int ks = r & 7; r >>= 3;
        int l = r;
        int col = fn * 16 + (lane & 15);
        int k0 = ks * 32 + (lane >> 4) * 8;
        short8 hh, ll;
        #pragma unroll
        for (int j = 0; j < 8; ++j){
            int k = k0 + j;
            float w = (k < D) ? Wl[(size_t)l * D * D + col * D + k]
                              : Wr[(size_t)l * D * D + col * D + (k - D)];
            unsigned short h = f2bf_hi(w);
            hh[j] = (short)h;
            ll[j] = (short)f2bf_hi(w - bf2f(h));
        }
        *(short8*)&WFh[(size_t)i * 8] = hh;
        *(short8*)&WFl[(size_t)i * 8] = ll;
    }
    if (i < D * D){ int k = i / D, d = i % D; W1T[i] = W1[d * D + k]; }
}

// ---------------- mean aggregation: gather fp16 rows, fp32 accumulate, 4-way ILP ----------
static __device__ inline void acc_h4(float4& a, uint2 u){
    __half2 h0 = *reinterpret_cast<__half2*>(&u.x);
    __half2 h1 = *reinterpret_cast<__half2*>(&u.y);
    float2 f0 = __half22float2(h0);
    float2 f1 = __half22float2(h1);
    a.x += f0.x; a.y += f0.y; a.z += f1.x; a.w += f1.y;
}

__global__ __launch_bounds__(256) void k_agg(const __half* __restrict__ xh, const int* __restrict__ ebuf,
                                             const int* __restrict__ offs, const float* __restrict__ invdeg,
                                             float* __restrict__ agg, int N){
    int node = blockIdx.x * 8 + (threadIdx.x >> 5);
    if (node >= N) return;
    int lane = threadIdx.x & 31;
    int s = offs[node], e = offs[node + 1];
    float4 a0 = make_float4(0.f,0.f,0.f,0.f), a1 = a0, a2 = a0, a3 = a0;
    int i = s;
    for (; i + 4 <= e; i += 4){
        int nb0 = ebuf[i], nb1 = ebuf[i+1], nb2 = ebuf[i+2], nb3 = ebuf[i+3];
        uint2 u0 = *(const uint2*)&xh[(size_t)nb0 * D + lane * 4];
        uint2 u1 = *(const uint2*)&xh[(size_t)nb1 * D + lane * 4];
        uint2 u2 = *(const uint2*)&xh[(size_t)nb2 * D + lane * 4];
        uint2 u3 = *(const uint2*)&xh[(size_t)nb3 * D + lane * 4];
        acc_h4(a0, u0); acc_h4(a1, u1); acc_h4(a2, u2); acc_h4(a3, u3);
    }
    for (; i < e; ++i){
        uint2 u = *(const uint2*)&xh[(size_t)ebuf[i] * D + lane * 4];
        acc_h4(a0, u);
    }
    a0.x += a1.x + a2.x + a3.x;
    a0.y += a1.y + a2.y + a3.y;
    a0.z += a1.z + a2.z + a3.z;
    a0.w += a1.w + a2.w + a3.w;
    float sc = invdeg[node];
    a0.x *= sc; a0.y *= sc; a0.z *= sc; a0.w *= sc;
    // agg row layout: lane covers elems [lane*4, lane*4+4)
    *(float4*)&agg[(size_t)node * D + lane * 4] = a0;
}

// ---------------- fused dense via split-bf16 MFMA, 2 row-tiles/wave ----------------
// Out[N,128] = [agg | x] (N,256) @ W (256,128) + bias, optional relu; also writes fp16 shadow.
// Block: 256 thr (4 waves), 128 rows/block; wave w owns rows w*32..w*32+31 (2 tiles of 16).
template<bool RELU>
__global__ __launch_bounds__(256) void k_dense_mfma(const float* __restrict__ Ag, const float* __restrict__ X,
                                                    const unsigned short* __restrict__ WFh,
                                                    const unsigned short* __restrict__ WFl,
                                                    const float* __restrict__ bias,
                                                    float* __restrict__ Out, __half* __restrict__ XhOut, int N){
    const int wave = threadIdx.x >> 6;
    const int lane = threadIdx.x & 63;
    const int l15  = lane & 15;
    const int kg   = lane >> 4;          // 0..3
    const int rbase = blockIdx.x * 128 + wave * 32;

    f32x4 acc[2][8];
    #pragma unroll
    for (int t = 0; t < 2; ++t)
        #pragma unroll
        for (int fn = 0; fn < 8; ++fn) acc[t][fn] = (f32x4){0.f, 0.f, 0.f, 0.f};

    #pragma unroll
    for (int ks = 0; ks < 8; ++ks){
        const float* S = (ks < 4) ? Ag : X;
        const int ko = (ks & 3) * 32 + kg * 8;
        short8 ah[2], al[2];
        #pragma unroll
        for (int t = 0; t < 2; ++t){
            int row = rbase + t * 16 + l15;
            row = min(row, N - 1);
            const float* ap = &S[(size_t)row * D + ko];
            float4 x0 = *(const float4*)ap;
            float4 x1 = *(const float4*)(ap + 4);
            float av[8] = {x0.x, x0.y, x0.z, x0.w, x1.x, x1.y, x1.z, x1.w};
            #pragma unroll
            for (int j = 0; j < 8; ++j){
                unsigned short h = f2bf_hi(av[j]);
                ah[t][j] = (short)h;
                al[t][j] = (short)f2bf_hi(av[j] - bf2f(h));
            }
        }
        #pragma unroll
        for (int fn = 0; fn < 8; ++fn){
            const size_t fo = ((size_t)(ks * 8 + fn) * 64 + lane) * 8;
            const short8 bh = *(const short8*)&WFh[fo];
            const short8 bl = *(const short8*)&WFl[fo];
            #pragma unroll
            for (int t = 0; t < 2; ++t){
                acc[t][fn] = __builtin_amdgcn_mfma_f32_16x16x32_bf16(ah[t], bh, acc[t][fn], 0, 0, 0);
                acc[t][fn] = __builtin_amdgcn_mfma_f32_16x16x32_bf16(al[t], bh, acc[t][fn], 0, 0, 0);
                acc[t][fn] = __builtin_amdgcn_mfma_f32_16x16x32_bf16(ah[t], bl, acc[t][fn], 0, 0, 0);
            }
        }
    }
    // epilogue: C/D layout col=lane&15, row=(lane>>4)*4+reg  [m89 verified]
    #pragma unroll
    for (int t = 0; t < 2; ++t){
        const int rb = rbase + t * 16 + (kg << 2);
        #pragma unroll
        for (int fn = 0; fn < 8; ++fn){
            const int col = fn * 16 + l15;
            const float bv = bias[col];
            #pragma unroll
            for (int r = 0; r < 4; ++r){
                const int orow = rb + r;
                if (orow < N){
                    float v = acc[t][fn][r] + bv;
                    if (RELU) v = fmaxf(v, 0.f);
                    Out[(size_t)orow * D + col] = v;
                    XhOut[(size_t)orow * D + col] = __float2half(v);
                }
            }
        }
    }
}

// ---------------- head: out[g] = W2 @ relu(W1 @ (x[c]*x[c+1]) + b1) + b2 ----------------
__global__ __launch_bounds__(128) void k_head(const float* __restrict__ x, const int* __restrict__ centers,
                                              const float* __restrict__ W1T, const float* __restrict__ b1,
                                              const float* __restrict__ W2, const float* __restrict__ b2,
                                              float* __restrict__ out){
    __shared__ float hs[D];
    __shared__ float red[D];
    int g = blockIdx.x; int d = threadIdx.x;
    int c = centers[g];
    hs[d] = x[(size_t)c * D + d] * x[(size_t)(c + 1) * D + d];
    __syncthreads();
    float acc = b1[d];
    #pragma unroll 8
    for (int k = 0; k < D; ++k) acc = fmaf(hs[k], W1T[k * D + d], acc);
    acc = fmaxf(acc, 0.f);
    red[d] = acc * W2[d];
    __syncthreads();
    for (int st = 64; st > 0; st >>= 1){
        if (d < st) red[d] += red[d + st];
        __syncthreads();
    }
    if (d == 0) out[g] = red[0] + b2[0];
}

extern "C" void kernel_launch(void* const* d_in, const int* in_sizes, int n_in,
                              void* d_out, int out_size, void* d_ws, size_t ws_size,
                              hipStream_t stream){
    const int*   z     = (const int*)  d_in[0];
    const int*   eidx  = (const int*)  d_in[1];
    const int*   batch = (const int*)  d_in[2];
    const float* zt    = (const float*)d_in[3];
    const float* Wl    = (const float*)d_in[4];
    const float* bl    = (const float*)d_in[5];
    const float* Wr    = (const float*)d_in[6];
    const float* W1    = (const float*)d_in[7];
    const float* b1    = (const float*)d_in[8];
    const float* W2    = (const float*)d_in[9];
    const float* b2    = (const float*)d_in[10];
    float* out = (float*)d_out;

    const int N = in_sizes[0];
    const int E = in_sizes[1] / 2;
    const int G = out_size;
    const int NB = (N + 255) >> NODE_SH;
    const int* src  = eidx;
    const int* dstp = eidx + E;

    char* p = (char*)d_ws;
    auto alloc = [&](size_t bytes){ char* r = p; p += align256(bytes); return r; };
    float* xa      = (float*)alloc((size_t)N * D * 4);
    float* xb      = (float*)alloc((size_t)N * D * 4);
    float* agg     = (float*)alloc((size_t)N * D * 4);
    __half* xha    = (__half*)alloc((size_t)N * D * 2);
    __half* xhb    = (__half*)alloc((size_t)N * D * 2);
    float* invdeg  = (float*)alloc((size_t)N * 4);
    int*   offs    = (int*)  alloc((size_t)(N + 1) * 4);
    int*   ebuf    = (int*)  alloc((size_t)E * 4);
    int*   ebuf2   = (int*)  alloc((size_t)E * 4);
    int*   centers = (int*)  alloc((size_t)G * 4);
    int*   bcnt    = (int*)  alloc((size_t)NB_MAX * 4);
    int*   gbase   = (int*)  alloc((size_t)(NB_MAX + 1) * 4);
    int*   gcur    = (int*)  alloc((size_t)NB_MAX * 4);
    float* W1T     = (float*)alloc((size_t)D * D * 4);
    unsigned short* WFh = (unsigned short*)alloc((size_t)NL * 8 * 8 * 64 * 8 * 2);
    unsigned short* WFl = (unsigned short*)alloc((size_t)NL * 8 * 8 * 64 * 8 * 2);
    (void)ws_size; (void)n_in;

    hipMemsetAsync(bcnt, 0, (size_t)NB_MAX * 4, stream);
    k_embed<<<(N * 32 + 255) / 256, 256, 0, stream>>>(z, zt, xa, xha, N);
    k_bcount<<<512, 256, 0, stream>>>(dstp, bcnt, E, NB);
    k_bscan<<<1, 512, 0, stream>>>(bcnt, gbase, gcur, offs, NB, N, E);
    k_binA<<<(E + BIN_CHUNK - 1) / BIN_CHUNK, 256, 0, stream>>>(src, dstp, gcur, ebuf2, E, NB);
    k_binB<<<NB, 256, 0, stream>>>(ebuf2, gbase, ebuf, offs, invdeg, N);
    k_centers<<<(N + 255) / 256, 256, 0, stream>>>(batch, centers, N);
    k_prepW<<<64, 256, 0, stream>>>(Wl, Wr, W1, W1T, WFh, WFl);

    float* xc = xa; float* xn = xb;
    __half* xhc = xha; __half* xhn = xhb;
    for (int l = 0; l < NL; ++l){
        k_agg<<<(N + 7) / 8, 256, 0, stream>>>(xhc, ebuf, offs, invdeg, agg, N);
        const unsigned short* wh = WFh + (size_t)l * 8 * 8 * 64 * 8;
        const unsigned short* wl = WFl + (size_t)l * 8 * 8 * 64 * 8;
        if (l < NL - 1)
            k_dense_mfma<true ><<<(N + 127) / 128, 256, 0, stream>>>(agg, xc, wh, wl, bl + l * D, xn, xhn, N);
        else
            k_dense_mfma<false><<<(N + 127) / 128, 256, 0, stream>>>(agg, xc, wh, wl, bl + l * D, xn, xhn, N);
        float* t = xc; xc = xn; xn = t;
        __half* th = xhc; xhc = xhn; xhn = th;
    }
    k_head<<<G, 128, 0, stream>>>(xc, centers, W1T, b1, W2, b2, out);
}